// Round 7
// baseline (202.585 us; speedup 1.0000x reference)
//
#include <hip/hip_runtime.h>

#define B_ 8
#define C_ 512
#define H_ 32
#define W_ 32
#define L_ 1024
#define M_ 8192   // B*L
#define NH_ 8
#define HD_ 64

typedef float f32x4 __attribute__((ext_vector_type(4)));
typedef short s16x8 __attribute__((ext_vector_type(8)));

// MFMA 16x16x32 bf16. C/D: col=lane&15 (n), row=(lane>>4)*4+reg (m).
// A frag: row m=lane&15, k=(lane>>4)*8+j ; B frag from B^T [n][k]: row n=lane&15.
__device__ __forceinline__ f32x4 mfma_bf16(f32x4 acc, s16x8 a, s16x8 b) {
    asm("v_mfma_f32_16x16x32_bf16 %0, %1, %2, %0" : "+v"(acc) : "v"(a), "v"(b));
    return acc;
}

__device__ __forceinline__ s16x8 ldg8(const unsigned short* p) {
    return *(const s16x8*)p;
}

typedef __attribute__((address_space(1))) const unsigned int glob_u32;
typedef __attribute__((address_space(3))) unsigned int lds_u32;
__device__ __forceinline__ void async_cp16(const void* g, void* l) {
    __builtin_amdgcn_global_load_lds((glob_u32*)g, (lds_u32*)l, 16, 0, 0);
}

__device__ __forceinline__ unsigned short f2bf(float f) {
    unsigned int u = __float_as_uint(f);
    unsigned int r = (u + 0x7FFFu + ((u >> 16) & 1u)) >> 16;
    return (unsigned short)r;
}

__device__ __forceinline__ float bf2f(unsigned short u) {
    return __uint_as_float(((unsigned int)u) << 16);
}

__device__ __forceinline__ float gelu_exact(float v) {
    return 0.5f * v * (1.0f + erff(v * 0.70710678118654752f));
}

__device__ __forceinline__ float sigmoidf_(float v) {
    return 1.0f / (1.0f + __expf(-v));
}

// ---------------- K0: fp32 -> bf16 weight conversion --------------------------
__global__ __launch_bounds__(256) void k_cvt_weights(
        const float* __restrict__ w1, const float* __restrict__ w2,
        const float* __restrict__ w3,
        unsigned short* __restrict__ o1, unsigned short* __restrict__ o2,
        unsigned short* __restrict__ o3, int n1, int n2, int n3) {
    int i = blockIdx.x * 256 + threadIdx.x;
    if (i < n1) o1[i] = f2bf(w1[i]);
    if (i < n2) o2[i] = f2bf(w2[i]);
    if (i < n3) o3[i] = f2bf(w3[i]);
}

// ---------------- K1: fused DualWalze + transpose/pack ------------------------
// block = (4-h-row tile lg, 64-channel group cg, batch b).
// x staged in LDS [c][6 rows][32] (c-stride 193 words, 2-way-conflict free);
// lane = channel in compute phase -> comb [l][c] writes 128B-coalesced;
// xw staged back through LDS (reuse, stride 129) -> l-fast coalesced stores.
__global__ __launch_bounds__(256) void k_walze_pack(
        const float* __restrict__ x, const float* __restrict__ dww,
        const float* __restrict__ dwb, const float* __restrict__ shw,
        const float* __restrict__ shb, const float* __restrict__ mixw,
        const float* __restrict__ gamma, const float* __restrict__ beta,
        float* __restrict__ xw, unsigned short* __restrict__ comb) {
    __shared__ float lds[64 * 193];           // 49.4 KB
    int h0 = blockIdx.x * 4;                  // 0,4,...,28
    int c0 = blockIdx.y * 64;
    int b  = blockIdx.z;
    int tid = threadIdx.x;
    const float* xb = x + ((size_t)(b * C_ + c0) << 10);
    // main rows h0..h0+3 (tile rows 1..4): 64c x 32 f4, coalesced 512B segments
#pragma unroll
    for (int k = 0; k < 8; ++k) {
        int idx = k * 256 + tid;
        int c = idx >> 5, f = idx & 31;
        float4 v = *(const float4*)(xb + ((size_t)c << 10) + h0 * 32 + f * 4);
        *(float4*)&lds[c * 193 + 32 + f * 4] = v;
    }
    // halo rows (h0-1)&31 -> tile row 0 ; (h0+4)&31 -> tile row 5
    int hm1 = (h0 + 31) & 31, hp4 = (h0 + 4) & 31;
#pragma unroll
    for (int k = 0; k < 4; ++k) {
        int idx = k * 256 + tid;
        int c = idx >> 4, s = idx & 15;
        int hi = s >> 3, f = s & 7;
        int srow = hi ? hp4 : hm1;
        float4 v = *(const float4*)(xb + ((size_t)c << 10) + srow * 32 + f * 4);
        *(float4*)&lds[c * 193 + (hi ? 5 * 32 : 0) + f * 4] = v;
    }
    __syncthreads();
    int lane = tid & 63;                      // = local channel
    int wave = tid >> 6;                      // = h-sub row (0..3)
    int c = c0 + lane;
    float wm[9], wsh[9];
#pragma unroll
    for (int t = 0; t < 9; ++t) { wm[t] = dww[c * 9 + t]; wsh[t] = shw[t]; }
    float mix = sigmoidf_(mixw[0]);
    float bmain = dwb[c], bsh = shb[0];
    float g = gamma[c], bt = beta[c];
    const float rs = rsqrtf(1.0f + 1e-5f);
    const float* myt = &lds[lane * 193];
    int l_row = h0 * 32 + wave * 32;          // global l of this lane's row
    unsigned short* crow = comb + (((size_t)(b << 10) + l_row) << 10);
    float vreg[32];
#pragma unroll
    for (int w = 0; w < 32; ++w) {
        float accm = 0.f, accs = 0.f;
#pragma unroll
        for (int kh = 0; kh < 3; ++kh) {
            int tr = wave + kh;
#pragma unroll
            for (int kw = 0; kw < 3; ++kw) {
                int ww = (w + kw + 31) & 31;
                float v = myt[tr * 32 + ww];
                accm += v * wm[kh * 3 + kw];
                accs += v * wsh[kh * 3 + kw];
            }
        }
        float xo = myt[(wave + 1) * 32 + w];
        float combined = mix * (accm + bmain) + (1.f - mix) * (accs + bsh) + xo;
        float val = gelu_exact(g * combined * rs + bt);
        vreg[w] = val;
        // comb writes: 64 lanes = 64 consecutive c -> 128B per instruction
        crow[(size_t)w * 1024 + c0 + lane] = f2bf(xo);
        crow[(size_t)w * 1024 + 512 + c0 + lane] = f2bf(val);
    }
    __syncthreads();                          // all tile reads done
    // stage xw vals [c][128 l] (stride 129) for coalesced global write
#pragma unroll
    for (int w = 0; w < 32; ++w)
        lds[lane * 129 + wave * 32 + w] = vreg[w];
    __syncthreads();
#pragma unroll
    for (int k = 0; k < 8; ++k) {
        int idx = k * 256 + tid;
        int cc = idx >> 5, f = idx & 31;
        float4 v = *(const float4*)&lds[cc * 129 + f * 4];
        *(float4*)(xw + ((size_t)(b * C_ + c0 + cc) << 10) + h0 * 32 + f * 4) = v;
    }
}

// ---------------- K3: spike detector, 8-wave blocks (16 n/wave) ---------------
__global__ __launch_bounds__(512) void k_detector(
        const unsigned short* __restrict__ comb, const unsigned short* __restrict__ w1,
        const float* __restrict__ b1, const float* __restrict__ w2,
        const float* __restrict__ b2, float* __restrict__ sm) {
    __shared__ float red[8][16];
    int tid = threadIdx.x;
    int wave = tid >> 6, lane = tid & 63;
    int col = lane & 15, quad = lane >> 4;
    int m0 = blockIdx.x * 16;
    int koff = quad * 8;
    int nb = wave * 16;
    const unsigned short* pa = comb + (size_t)(m0 + col) * 1024 + koff;
    const unsigned short* pw = w1 + (size_t)(nb + col) * 1024 + koff;
    f32x4 acc = {0.f, 0.f, 0.f, 0.f};
    for (int k = 0; k < 1024; k += 32)
        acc = mfma_bf16(acc, ldg8(pa + k), ldg8(pw + k));
    asm volatile("s_nop 7\ns_nop 7");
    float bia = b1[nb + col], wv = w2[nb + col];
#pragma unroll
    for (int r = 0; r < 4; ++r) {
        float p = gelu_exact(acc[r] + bia) * wv;
        p += __shfl_xor(p, 1);
        p += __shfl_xor(p, 2);
        p += __shfl_xor(p, 4);
        p += __shfl_xor(p, 8);
        if (col == 0) red[wave][quad * 4 + r] = p;
    }
    __syncthreads();
    if (tid < 16) {
        float s = b2[0];
#pragma unroll
        for (int w = 0; w < 8; ++w) s += red[w][tid];
        sm[m0 + tid] = sigmoidf_(s);
    }
}

// ---------------- K4: qkv GEMM, staged 128x128xBK64, split bf16 out -----------
__global__ __launch_bounds__(256) void k_gemm_qkv(
        const unsigned short* __restrict__ A,    // comb+512, lda=1024
        const unsigned short* __restrict__ Wt,   // [1536][512]
        const float* __restrict__ bias,
        unsigned short* __restrict__ out_hi, unsigned short* __restrict__ out_lo) {
    __shared__ unsigned short As[128 * 64];
    __shared__ unsigned short Bs[128 * 64];
    int tid = threadIdx.x;
    int wave = tid >> 6, lane = tid & 63;
    int col = lane & 15, quad = lane >> 4;
    int wr = wave & 1, wc = wave >> 1;
    int mb = blockIdx.y * 128, nb = blockIdx.x * 128;
    int srow = tid >> 3, sko = tid & 7;
    f32x4 acc[4][4] = {};
    for (int kb = 0; kb < 512; kb += 64) {
#pragma unroll
        for (int p = 0; p < 4; ++p) {
            int r = p * 32 + srow;
            async_cp16(A + (size_t)(mb + r) * 1024 + kb + sko * 8, &As[r * 64 + sko * 8]);
            async_cp16(Wt + (size_t)(nb + r) * 512 + kb + sko * 8, &Bs[r * 64 + sko * 8]);
        }
        __syncthreads();
#pragma unroll
        for (int ks = 0; ks < 64; ks += 32) {
            s16x8 a[4], b[4];
#pragma unroll
            for (int i = 0; i < 4; ++i)
                a[i] = *(const s16x8*)&As[(wr * 64 + i * 16 + col) * 64 + ks + quad * 8];
#pragma unroll
            for (int j = 0; j < 4; ++j)
                b[j] = *(const s16x8*)&Bs[(wc * 64 + j * 16 + col) * 64 + ks + quad * 8];
#pragma unroll
            for (int i = 0; i < 4; ++i)
#pragma unroll
                for (int j = 0; j < 4; ++j)
                    acc[i][j] = mfma_bf16(acc[i][j], a[i], b[j]);
        }
        __syncthreads();
    }
    asm volatile("s_nop 7\ns_nop 7");
#pragma unroll
    for (int i = 0; i < 4; ++i)
#pragma unroll
        for (int j = 0; j < 4; ++j) {
            int n = nb + wc * 64 + j * 16 + col;
            float bv = bias[n];
#pragma unroll
            for (int r = 0; r < 4; ++r) {
                int m = mb + wr * 64 + i * 16 + quad * 4 + r;
                float v = acc[i][j][r] + bv;
                unsigned short hi = f2bf(v);
                size_t idx = (size_t)m * 1536 + n;
                out_hi[idx] = hi;
                out_lo[idx] = f2bf(v - bf2f(hi));
            }
        }
}

// ---------------- K5: windowed attention via MFMA, split-precision ------------
// S = qh.kh + qh.kl + ql.kh ; P NORMALIZED then split hi/lo;
// O = Ph.Vh + Pl.Vh + Ph.Vl written directly.
__global__ __launch_bounds__(256) void k_attn(
        const unsigned short* __restrict__ qkv_hi,
        const unsigned short* __restrict__ qkv_lo,
        unsigned short* __restrict__ ctx) {
    __shared__ unsigned short Vth[64 * 104];      // V hi [d][key], ld=104
    __shared__ unsigned short Vtl[64 * 104];      // V lo
    __shared__ unsigned short Ph[4][16 * 104];    // per-wave P hi [m][key]
    __shared__ unsigned short Pl[4][16 * 104];    // per-wave P lo
    int b = blockIdx.z, h = blockIdx.y;
    int q0 = blockIdx.x * 64;
    int tid = threadIdx.x, wave = tid >> 6, lane = tid & 63;
    int col = lane & 15, quad = lane >> 4;
    int jlo_t = max(q0 - 16, 0);
    const unsigned short* baseh = qkv_hi + ((size_t)(b << 10)) * 1536;
    const unsigned short* basel = qkv_lo + ((size_t)(b << 10)) * 1536;
#pragma unroll
    for (int it = 0; it < 3; ++it) {
        int slot = it * 256 + tid;
        int kg = slot >> 6, d = slot & 63;
        int key0 = jlo_t + kg * 8;
        unsigned short eh[8], el[8];
#pragma unroll
        for (int t = 0; t < 8; ++t) {
            size_t ro = (size_t)min(key0 + t, 1023) * 1536 + 1024 + h * 64 + d;
            eh[t] = baseh[ro];
            el[t] = basel[ro];
        }
        ushort4 h0 = {eh[0], eh[1], eh[2], eh[3]}, h1 = {eh[4], eh[5], eh[6], eh[7]};
        ushort4 l0 = {el[0], el[1], el[2], el[3]}, l1 = {el[4], el[5], el[6], el[7]};
        *(ushort4*)&Vth[d * 104 + kg * 8] = h0;
        *(ushort4*)&Vth[d * 104 + kg * 8 + 4] = h1;
        *(ushort4*)&Vtl[d * 104 + kg * 8] = l0;
        *(ushort4*)&Vtl[d * 104 + kg * 8 + 4] = l1;
    }
    __syncthreads();
    size_t qoff = (size_t)(q0 + wave * 16 + col) * 1536 + h * 64;
    s16x8 aq0h = ldg8(baseh + qoff + quad * 8);
    s16x8 aq1h = ldg8(baseh + qoff + 32 + quad * 8);
    s16x8 aq0l = ldg8(basel + qoff + quad * 8);
    s16x8 aq1l = ldg8(basel + qoff + 32 + quad * 8);
    f32x4 S[6];
#pragma unroll
    for (int nt = 0; nt < 6; ++nt) {
        size_t koffb = (size_t)min(jlo_t + nt * 16 + col, 1023) * 1536 + 512 + h * 64;
        s16x8 kh0 = ldg8(baseh + koffb + quad * 8);
        s16x8 kh1 = ldg8(baseh + koffb + 32 + quad * 8);
        s16x8 kl0 = ldg8(basel + koffb + quad * 8);
        s16x8 kl1 = ldg8(basel + koffb + 32 + quad * 8);
        f32x4 z = {0.f, 0.f, 0.f, 0.f};
        z = mfma_bf16(z, aq0h, kh0);
        z = mfma_bf16(z, aq1h, kh1);
        z = mfma_bf16(z, aq0h, kl0);
        z = mfma_bf16(z, aq1h, kl1);
        z = mfma_bf16(z, aq0l, kh0);
        z = mfma_bf16(z, aq1l, kh1);
        S[nt] = z;
    }
    asm volatile("s_nop 7\ns_nop 7");
    int i_base = q0 + wave * 16 + quad * 4;
    float mx[4] = {-1e30f, -1e30f, -1e30f, -1e30f};
#pragma unroll
    for (int nt = 0; nt < 6; ++nt) {
        int j = jlo_t + nt * 16 + col;
#pragma unroll
        for (int r = 0; r < 4; ++r) {
            int i = i_base + r;
            bool ok = (j <= 1023) && (j >= i - 16) && (j <= i + 16);
            float s = ok ? S[nt][r] * 0.125f : -1e30f;
            S[nt][r] = s;
            mx[r] = fmaxf(mx[r], s);
        }
    }
#pragma unroll
    for (int r = 0; r < 4; ++r) {
        mx[r] = fmaxf(mx[r], __shfl_xor(mx[r], 1));
        mx[r] = fmaxf(mx[r], __shfl_xor(mx[r], 2));
        mx[r] = fmaxf(mx[r], __shfl_xor(mx[r], 4));
        mx[r] = fmaxf(mx[r], __shfl_xor(mx[r], 8));
    }
    float sum[4] = {0.f, 0.f, 0.f, 0.f};
#pragma unroll
    for (int nt = 0; nt < 6; ++nt)
#pragma unroll
        for (int r = 0; r < 4; ++r) {
            float p = __expf(S[nt][r] - mx[r]);
            S[nt][r] = p;
            sum[r] += p;
        }
#pragma unroll
    for (int r = 0; r < 4; ++r) {
        sum[r] += __shfl_xor(sum[r], 1);
        sum[r] += __shfl_xor(sum[r], 2);
        sum[r] += __shfl_xor(sum[r], 4);
        sum[r] += __shfl_xor(sum[r], 8);
        sum[r] = 1.f / sum[r];
    }
#pragma unroll
    for (int nt = 0; nt < 6; ++nt)
#pragma unroll
        for (int r = 0; r < 4; ++r) {
            float pv = S[nt][r] * sum[r];
            unsigned short hi = f2bf(pv);
            Ph[wave][(quad * 4 + r) * 104 + nt * 16 + col] = hi;
            Pl[wave][(quad * 4 + r) * 104 + nt * 16 + col] = f2bf(pv - bf2f(hi));
        }
    __syncthreads();
    f32x4 O[4] = {};
#pragma unroll
    for (int ks = 0; ks < 96; ks += 32) {
        s16x8 aph = *(const s16x8*)&Ph[wave][col * 104 + ks + quad * 8];
        s16x8 apl = *(const s16x8*)&Pl[wave][col * 104 + ks + quad * 8];
#pragma unroll
        for (int nt = 0; nt < 4; ++nt) {
            s16x8 bvh = *(const s16x8*)&Vth[(nt * 16 + col) * 104 + ks + quad * 8];
            s16x8 bvl = *(const s16x8*)&Vtl[(nt * 16 + col) * 104 + ks + quad * 8];
            O[nt] = mfma_bf16(O[nt], aph, bvh);
            O[nt] = mfma_bf16(O[nt], apl, bvh);
            O[nt] = mfma_bf16(O[nt], aph, bvl);
        }
    }
    asm volatile("s_nop 7\ns_nop 7");
#pragma unroll
    for (int nt = 0; nt < 4; ++nt)
#pragma unroll
        for (int r = 0; r < 4; ++r) {
            int i = i_base + r;
            ctx[((size_t)(b << 10) + i) * 512 + h * 64 + nt * 16 + col] = f2bf(O[nt][r]);
        }
}

// ---------------- K6: out-proj GEMM staged + gated combine --------------------
__global__ __launch_bounds__(256) void k_out_combine(
        const unsigned short* __restrict__ Wt, const unsigned short* __restrict__ Actx,
        const float* __restrict__ bias, const float* __restrict__ xw,
        const float* __restrict__ sm, float* __restrict__ out) {
    __shared__ unsigned short As[128 * 64];
    __shared__ unsigned short Bs[128 * 64];
    int tid = threadIdx.x;
    int wave = tid >> 6, lane = tid & 63;
    int col = lane & 15, quad = lane >> 4;
    int wr = wave & 1, wc = wave >> 1;
    int mb = blockIdx.y * 128, nb = blockIdx.x * 128;
    int srow = tid >> 3, sko = tid & 7;
    f32x4 acc[4][4] = {};
    for (int kb = 0; kb < 512; kb += 64) {
#pragma unroll
        for (int p = 0; p < 4; ++p) {
            int r = p * 32 + srow;
            async_cp16(Wt + (size_t)(mb + r) * 512 + kb + sko * 8, &As[r * 64 + sko * 8]);
            async_cp16(Actx + (size_t)(nb + r) * 512 + kb + sko * 8, &Bs[r * 64 + sko * 8]);
        }
        __syncthreads();
#pragma unroll
        for (int ks = 0; ks < 64; ks += 32) {
            s16x8 a[4], b[4];
#pragma unroll
            for (int i = 0; i < 4; ++i)
                a[i] = *(const s16x8*)&As[(wr * 64 + i * 16 + col) * 64 + ks + quad * 8];
#pragma unroll
            for (int j = 0; j < 4; ++j)
                b[j] = *(const s16x8*)&Bs[(wc * 64 + j * 16 + col) * 64 + ks + quad * 8];
#pragma unroll
            for (int i = 0; i < 4; ++i)
#pragma unroll
                for (int j = 0; j < 4; ++j)
                    acc[i][j] = mfma_bf16(acc[i][j], a[i], b[j]);
        }
        __syncthreads();
    }
    asm volatile("s_nop 7\ns_nop 7");
#pragma unroll
    for (int i = 0; i < 4; ++i)
#pragma unroll
        for (int j = 0; j < 4; ++j) {
            int seq = nb + wc * 64 + j * 16 + col;
            int bb = seq >> 10, l = seq & 1023;
            float smv = sm[seq];
#pragma unroll
            for (int r = 0; r < 4; ++r) {
                int c = mb + wr * 64 + i * 16 + quad * 4 + r;
                float v = acc[i][j][r] + bias[c];
                size_t oidx = ((size_t)(bb * C_ + c) << 10) + l;
                out[oidx] = xw[oidx] + smv * v;
            }
        }
}

extern "C" void kernel_launch(void* const* d_in, const int* in_sizes, int n_in,
                              void* d_out, int out_size, void* d_ws, size_t ws_size,
                              hipStream_t stream) {
    const float* x      = (const float*)d_in[0];
    const float* dw_w   = (const float*)d_in[1];
    const float* dw_b   = (const float*)d_in[2];
    const float* sh_w   = (const float*)d_in[3];
    const float* sh_b   = (const float*)d_in[4];
    const float* mix_w  = (const float*)d_in[5];
    const float* bn_g   = (const float*)d_in[6];
    const float* bn_b   = (const float*)d_in[7];
    const float* det_w1 = (const float*)d_in[8];
    const float* det_b1 = (const float*)d_in[9];
    const float* det_w2 = (const float*)d_in[10];
    const float* det_b2 = (const float*)d_in[11];
    const float* inp_w  = (const float*)d_in[12];
    const float* inp_b  = (const float*)d_in[13];
    const float* outp_w = (const float*)d_in[14];
    const float* outp_b = (const float*)d_in[15];
    float* out = (float*)d_out;

    char* ws = (char*)d_ws;
    size_t off = 0;
    auto alloc = [&](size_t bytes) -> void* {
        void* p = ws + off;
        off += (bytes + 255) & ~(size_t)255;
        return p;
    };
    float* xw             = (float*)alloc((size_t)M_ * C_ * 4);
    unsigned short* comb  = (unsigned short*)alloc((size_t)M_ * 1024 * 2);
    unsigned short* qkvh  = (unsigned short*)alloc((size_t)M_ * 1536 * 2);
    unsigned short* qkvl  = (unsigned short*)alloc((size_t)M_ * 1536 * 2);
    unsigned short* ctx   = (unsigned short*)alloc((size_t)M_ * 512 * 2);
    float* smask          = (float*)alloc((size_t)M_ * 4);
    unsigned short* w1b   = (unsigned short*)alloc(131072 * 2);
    unsigned short* inwb  = (unsigned short*)alloc(786432 * 2);
    unsigned short* outwb = (unsigned short*)alloc(262144 * 2);
    (void)ws_size; (void)in_sizes; (void)n_in; (void)out_size;

    k_cvt_weights<<<3072, 256, 0, stream>>>(det_w1, inp_w, outp_w, w1b, inwb, outwb,
                                            131072, 786432, 262144);
    k_walze_pack<<<dim3(8, 8, 8), 256, 0, stream>>>(x, dw_w, dw_b, sh_w, sh_b, mix_w,
                                                    bn_g, bn_b, xw, comb);
    k_detector<<<M_ / 16, 512, 0, stream>>>(comb, w1b, det_b1, det_w2, det_b2, smask);
    k_gemm_qkv<<<dim3(1536 / 128, M_ / 128), 256, 0, stream>>>(comb + 512, inwb, inp_b,
                                                               qkvh, qkvl);
    k_attn<<<dim3(16, NH_, B_), 256, 0, stream>>>(qkvh, qkvl, ctx);
    k_out_combine<<<dim3(M_ / 128, C_ / 128), 256, 0, stream>>>(outwb, ctx, outp_b,
                                                                xw, smask, out);
}

// Round 8
// 199.266 us; speedup vs baseline: 1.0167x; 1.0167x over previous
//
#include <hip/hip_runtime.h>

#define B_ 8
#define C_ 512
#define H_ 32
#define W_ 32
#define L_ 1024
#define M_ 8192   // B*L
#define NH_ 8
#define HD_ 64

typedef float f32x4 __attribute__((ext_vector_type(4)));
typedef short s16x8 __attribute__((ext_vector_type(8)));

// MFMA 16x16x32 bf16. C/D: col=lane&15 (n), row=(lane>>4)*4+reg (m).
// A frag: row m=lane&15, k=(lane>>4)*8+j ; B frag from B^T [n][k]: row n=lane&15.
__device__ __forceinline__ f32x4 mfma_bf16(f32x4 acc, s16x8 a, s16x8 b) {
    asm("v_mfma_f32_16x16x32_bf16 %0, %1, %2, %0" : "+v"(acc) : "v"(a), "v"(b));
    return acc;
}

__device__ __forceinline__ s16x8 ldg8(const unsigned short* p) {
    return *(const s16x8*)p;
}

typedef __attribute__((address_space(1))) const unsigned int glob_u32;
typedef __attribute__((address_space(3))) unsigned int lds_u32;
__device__ __forceinline__ void async_cp16(const void* g, void* l) {
    __builtin_amdgcn_global_load_lds((glob_u32*)g, (lds_u32*)l, 16, 0, 0);
}

__device__ __forceinline__ unsigned short f2bf(float f) {
    unsigned int u = __float_as_uint(f);
    unsigned int r = (u + 0x7FFFu + ((u >> 16) & 1u)) >> 16;
    return (unsigned short)r;
}

__device__ __forceinline__ float bf2f(unsigned short u) {
    return __uint_as_float(((unsigned int)u) << 16);
}

__device__ __forceinline__ float gelu_exact(float v) {
    return 0.5f * v * (1.0f + erff(v * 0.70710678118654752f));
}

__device__ __forceinline__ float sigmoidf_(float v) {
    return 1.0f / (1.0f + __expf(-v));
}

// ---------------- K0: fp32 -> bf16 weight conversion --------------------------
__global__ __launch_bounds__(256) void k_cvt_weights(
        const float* __restrict__ w1, const float* __restrict__ w2,
        const float* __restrict__ w3,
        unsigned short* __restrict__ o1, unsigned short* __restrict__ o2,
        unsigned short* __restrict__ o3, int n1, int n2, int n3) {
    int i = blockIdx.x * 256 + threadIdx.x;
    if (i < n1) o1[i] = f2bf(w1[i]);
    if (i < n2) o2[i] = f2bf(w2[i]);
    if (i < n3) o3[i] = f2bf(w3[i]);
}

// ---------------- K1: DualWalze (round-6 known-good) --------------------------
__global__ __launch_bounds__(256) void k_walze(
        const float* __restrict__ x, const float* __restrict__ dww,
        const float* __restrict__ dwb, const float* __restrict__ shw,
        const float* __restrict__ shb, const float* __restrict__ mixw,
        const float* __restrict__ gamma, const float* __restrict__ beta,
        float* __restrict__ xw) {
    __shared__ float tile[1024];
    int bc = blockIdx.x;           // b*C + c
    int c = bc & (C_ - 1);
    int tid = threadIdx.x;
    const float* xp = x + (size_t)bc * 1024;
#pragma unroll
    for (int t = 0; t < 4; ++t) tile[tid + 256 * t] = xp[tid + 256 * t];
    __syncthreads();
    float wm[9], wsh[9];
#pragma unroll
    for (int t = 0; t < 9; ++t) { wm[t] = dww[c * 9 + t]; wsh[t] = shw[t]; }
    float mix = sigmoidf_(mixw[0]);
    float bmain = dwb[c], bsh = shb[0];
    float g = gamma[c], bt = beta[c];
    const float rs = rsqrtf(1.0f + 1e-5f);
#pragma unroll
    for (int t = 0; t < 4; ++t) {
        int l = tid + 256 * t;
        int h = l >> 5, w = l & 31;
        float accm = 0.f, accs = 0.f;
#pragma unroll
        for (int kh = 0; kh < 3; ++kh) {
            int hh = (h + kh + 31) & 31;
#pragma unroll
            for (int kw = 0; kw < 3; ++kw) {
                int ww = (w + kw + 31) & 31;
                float v = tile[hh * 32 + ww];
                accm += v * wm[kh * 3 + kw];
                accs += v * wsh[kh * 3 + kw];
            }
        }
        float combined = mix * (accm + bmain) + (1.f - mix) * (accs + bsh) + tile[l];
        float bn = g * combined * rs + bt;
        xw[(size_t)bc * 1024 + l] = gelu_exact(bn);
    }
}

// ---------------- K2: LDS-tiled transpose+pack (round-6 known-good) -----------
__global__ __launch_bounds__(256) void k_pack(
        const float* __restrict__ x, const float* __restrict__ xw,
        unsigned short* __restrict__ comb) {
    __shared__ float Tx[64 * 65];
    __shared__ float Tw[64 * 65];
    int b = blockIdx.z;
    int c0 = blockIdx.y * 64;
    int l0 = blockIdx.x * 64;
    int tid = threadIdx.x;
    for (int idx = tid; idx < 1024; idx += 256) {
        int cr = idx >> 4, f = idx & 15;
        size_t src = ((size_t)(b * C_ + c0 + cr) << 10) + l0 + f * 4;
        float4 vx = *(const float4*)(x + src);
        float4 vw = *(const float4*)(xw + src);
        *(float4*)&Tx[cr * 65 + f * 4] = vx;
        *(float4*)&Tw[cr * 65 + f * 4] = vw;
    }
    __syncthreads();
    for (int idx = tid; idx < 1024; idx += 256) {
        int lr = idx >> 4, f = idx & 15;
        ushort4 ux, uw;
        ux.x = f2bf(Tx[(4 * f + 0) * 65 + lr]);
        ux.y = f2bf(Tx[(4 * f + 1) * 65 + lr]);
        ux.z = f2bf(Tx[(4 * f + 2) * 65 + lr]);
        ux.w = f2bf(Tx[(4 * f + 3) * 65 + lr]);
        uw.x = f2bf(Tw[(4 * f + 0) * 65 + lr]);
        uw.y = f2bf(Tw[(4 * f + 1) * 65 + lr]);
        uw.z = f2bf(Tw[(4 * f + 2) * 65 + lr]);
        uw.w = f2bf(Tw[(4 * f + 3) * 65 + lr]);
        unsigned short* row = comb + (((size_t)(b << 10) + l0 + lr) << 10);
        *(ushort4*)(row + c0 + 4 * f) = ux;
        *(ushort4*)(row + 512 + c0 + 4 * f) = uw;
    }
}

// ---------------- K3: spike detector (round-6 known-good, 4-wave) -------------
__global__ __launch_bounds__(256) void k_detector(
        const unsigned short* __restrict__ comb, const unsigned short* __restrict__ w1,
        const float* __restrict__ b1, const float* __restrict__ w2,
        const float* __restrict__ b2, float* __restrict__ sm) {
    __shared__ float red[64];
    int tid = threadIdx.x;
    int wave = tid >> 6, lane = tid & 63;
    int col = lane & 15, quad = lane >> 4;
    int m0 = blockIdx.x * 16;
    int koff = quad * 8;
    int nb0 = wave * 32, nb1 = nb0 + 16;
    const unsigned short* pa  = comb + (size_t)(m0 + col) * 1024 + koff;
    const unsigned short* pw0 = w1 + (size_t)(nb0 + col) * 1024 + koff;
    const unsigned short* pw1 = w1 + (size_t)(nb1 + col) * 1024 + koff;
    f32x4 acc0 = {0.f, 0.f, 0.f, 0.f}, acc1 = {0.f, 0.f, 0.f, 0.f};
    for (int k = 0; k < 1024; k += 32) {
        s16x8 a = ldg8(pa + k);
        acc0 = mfma_bf16(acc0, a, ldg8(pw0 + k));
        acc1 = mfma_bf16(acc1, a, ldg8(pw1 + k));
    }
    asm volatile("s_nop 7\ns_nop 7");
    float bia0 = b1[nb0 + col], bia1 = b1[nb1 + col];
    float wv0 = w2[nb0 + col], wv1 = w2[nb1 + col];
#pragma unroll
    for (int r = 0; r < 4; ++r) {
        float h0 = gelu_exact(acc0[r] + bia0);
        float h1 = gelu_exact(acc1[r] + bia1);
        float p = h0 * wv0 + h1 * wv1;
        p += __shfl_xor(p, 1);
        p += __shfl_xor(p, 2);
        p += __shfl_xor(p, 4);
        p += __shfl_xor(p, 8);
        if (col == 0) red[wave * 16 + quad * 4 + r] = p;
    }
    __syncthreads();
    if (tid < 16) {
        float s = red[tid] + red[16 + tid] + red[32 + tid] + red[48 + tid] + b2[0];
        sm[m0 + tid] = sigmoidf_(s);
    }
}

// ---------------- K4: qkv GEMM, staged 128x128xBK64, split bf16 out -----------
__global__ __launch_bounds__(256) void k_gemm_qkv(
        const unsigned short* __restrict__ A,    // comb+512, lda=1024
        const unsigned short* __restrict__ Wt,   // [1536][512]
        const float* __restrict__ bias,
        unsigned short* __restrict__ out_hi, unsigned short* __restrict__ out_lo) {
    __shared__ unsigned short As[128 * 64];
    __shared__ unsigned short Bs[128 * 64];
    int tid = threadIdx.x;
    int wave = tid >> 6, lane = tid & 63;
    int col = lane & 15, quad = lane >> 4;
    int wr = wave & 1, wc = wave >> 1;
    int mb = blockIdx.y * 128, nb = blockIdx.x * 128;
    int srow = tid >> 3, sko = tid & 7;
    f32x4 acc[4][4] = {};
    for (int kb = 0; kb < 512; kb += 64) {
#pragma unroll
        for (int p = 0; p < 4; ++p) {
            int r = p * 32 + srow;
            async_cp16(A + (size_t)(mb + r) * 1024 + kb + sko * 8, &As[r * 64 + sko * 8]);
            async_cp16(Wt + (size_t)(nb + r) * 512 + kb + sko * 8, &Bs[r * 64 + sko * 8]);
        }
        __syncthreads();
#pragma unroll
        for (int ks = 0; ks < 64; ks += 32) {
            s16x8 a[4], b[4];
#pragma unroll
            for (int i = 0; i < 4; ++i)
                a[i] = *(const s16x8*)&As[(wr * 64 + i * 16 + col) * 64 + ks + quad * 8];
#pragma unroll
            for (int j = 0; j < 4; ++j)
                b[j] = *(const s16x8*)&Bs[(wc * 64 + j * 16 + col) * 64 + ks + quad * 8];
#pragma unroll
            for (int i = 0; i < 4; ++i)
#pragma unroll
                for (int j = 0; j < 4; ++j)
                    acc[i][j] = mfma_bf16(acc[i][j], a[i], b[j]);
        }
        __syncthreads();
    }
    asm volatile("s_nop 7\ns_nop 7");
#pragma unroll
    for (int i = 0; i < 4; ++i)
#pragma unroll
        for (int j = 0; j < 4; ++j) {
            int n = nb + wc * 64 + j * 16 + col;
            float bv = bias[n];
#pragma unroll
            for (int r = 0; r < 4; ++r) {
                int m = mb + wr * 64 + i * 16 + quad * 4 + r;
                float v = acc[i][j][r] + bv;
                unsigned short hi = f2bf(v);
                size_t idx = (size_t)m * 1536 + n;
                out_hi[idx] = hi;
                out_lo[idx] = f2bf(v - bf2f(hi));
            }
        }
}

// ---------------- K5: windowed attention via MFMA, split-precision ------------
// S = qh.kh + qh.kl + ql.kh over 96 staged keys; P NORMALIZED, split hi/lo into
// per-wave 48-key window buffers (16 pad cols zeroed); PV over K=64 window only:
// O = Ph.Vh + Pl.Vh + Ph.Vl  (24 MFMAs vs 36).
__global__ __launch_bounds__(256) void k_attn(
        const unsigned short* __restrict__ qkv_hi,
        const unsigned short* __restrict__ qkv_lo,
        unsigned short* __restrict__ ctx) {
    __shared__ unsigned short Vth[64 * 112];      // V hi [d][key], ld=112 (96 real + 16 zero pad)
    __shared__ unsigned short Vtl[64 * 112];      // V lo
    __shared__ unsigned short Ph[4][16 * 72];     // per-wave P hi [m][window-key], ld=72
    __shared__ unsigned short Pl[4][16 * 72];     // per-wave P lo
    int b = blockIdx.z, h = blockIdx.y;
    int q0 = blockIdx.x * 64;
    int tid = threadIdx.x, wave = tid >> 6, lane = tid & 63;
    int col = lane & 15, quad = lane >> 4;
    int jlo_t = max(q0 - 16, 0);
    const unsigned short* baseh = qkv_hi + ((size_t)(b << 10)) * 1536;
    const unsigned short* basel = qkv_lo + ((size_t)(b << 10)) * 1536;
    // stage V^T hi and lo: 12 key-groups x 64 d
#pragma unroll
    for (int it = 0; it < 3; ++it) {
        int slot = it * 256 + tid;
        int kg = slot >> 6, d = slot & 63;
        int key0 = jlo_t + kg * 8;
        unsigned short eh[8], el[8];
#pragma unroll
        for (int t = 0; t < 8; ++t) {
            size_t ro = (size_t)min(key0 + t, 1023) * 1536 + 1024 + h * 64 + d;
            eh[t] = baseh[ro];
            el[t] = basel[ro];
        }
        ushort4 h0 = {eh[0], eh[1], eh[2], eh[3]}, h1 = {eh[4], eh[5], eh[6], eh[7]};
        ushort4 l0 = {el[0], el[1], el[2], el[3]}, l1 = {el[4], el[5], el[6], el[7]};
        *(ushort4*)&Vth[d * 112 + kg * 8] = h0;
        *(ushort4*)&Vth[d * 112 + kg * 8 + 4] = h1;
        *(ushort4*)&Vtl[d * 112 + kg * 8] = l0;
        *(ushort4*)&Vtl[d * 112 + kg * 8 + 4] = l1;
    }
    // zero V pad keys [96,112) so windowed PV reads are 0 (P there is 0 too)
    {
        int d = tid >> 2, c4 = (tid & 3) * 4;
        ushort4 z = {0, 0, 0, 0};
        *(ushort4*)&Vth[d * 112 + 96 + c4] = z;
        *(ushort4*)&Vtl[d * 112 + 96 + c4] = z;
    }
    __syncthreads();
    // Q A-frags hi+lo
    size_t qoff = (size_t)(q0 + wave * 16 + col) * 1536 + h * 64;
    s16x8 aq0h = ldg8(baseh + qoff + quad * 8);
    s16x8 aq1h = ldg8(baseh + qoff + 32 + quad * 8);
    s16x8 aq0l = ldg8(basel + qoff + quad * 8);
    s16x8 aq1l = ldg8(basel + qoff + 32 + quad * 8);
    // S over 6 key-tiles of 16
    f32x4 S[6];
#pragma unroll
    for (int nt = 0; nt < 6; ++nt) {
        size_t koffb = (size_t)min(jlo_t + nt * 16 + col, 1023) * 1536 + 512 + h * 64;
        s16x8 kh0 = ldg8(baseh + koffb + quad * 8);
        s16x8 kh1 = ldg8(baseh + koffb + 32 + quad * 8);
        s16x8 kl0 = ldg8(basel + koffb + quad * 8);
        s16x8 kl1 = ldg8(basel + koffb + 32 + quad * 8);
        f32x4 z = {0.f, 0.f, 0.f, 0.f};
        z = mfma_bf16(z, aq0h, kh0);
        z = mfma_bf16(z, aq1h, kh1);
        z = mfma_bf16(z, aq0h, kl0);
        z = mfma_bf16(z, aq1h, kl1);
        z = mfma_bf16(z, aq0l, kh0);
        z = mfma_bf16(z, aq1l, kh1);
        S[nt] = z;
    }
    asm volatile("s_nop 7\ns_nop 7");
    // masked softmax per row r
    int i_base = q0 + wave * 16 + quad * 4;
    float mx[4] = {-1e30f, -1e30f, -1e30f, -1e30f};
#pragma unroll
    for (int nt = 0; nt < 6; ++nt) {
        int j = jlo_t + nt * 16 + col;
#pragma unroll
        for (int r = 0; r < 4; ++r) {
            int i = i_base + r;
            bool ok = (j <= 1023) && (j >= i - 16) && (j <= i + 16);
            float s = ok ? S[nt][r] * 0.125f : -1e30f;
            S[nt][r] = s;
            mx[r] = fmaxf(mx[r], s);
        }
    }
#pragma unroll
    for (int r = 0; r < 4; ++r) {
        mx[r] = fmaxf(mx[r], __shfl_xor(mx[r], 1));
        mx[r] = fmaxf(mx[r], __shfl_xor(mx[r], 2));
        mx[r] = fmaxf(mx[r], __shfl_xor(mx[r], 4));
        mx[r] = fmaxf(mx[r], __shfl_xor(mx[r], 8));
    }
    float sum[4] = {0.f, 0.f, 0.f, 0.f};
#pragma unroll
    for (int nt = 0; nt < 6; ++nt)
#pragma unroll
        for (int r = 0; r < 4; ++r) {
            float p = __expf(S[nt][r] - mx[r]);
            S[nt][r] = p;
            sum[r] += p;
        }
#pragma unroll
    for (int r = 0; r < 4; ++r) {
        sum[r] += __shfl_xor(sum[r], 1);
        sum[r] += __shfl_xor(sum[r], 2);
        sum[r] += __shfl_xor(sum[r], 4);
        sum[r] += __shfl_xor(sum[r], 8);
        sum[r] = 1.f / sum[r];
    }
    // per-wave window base (block-relative); all nonzero P land in [0,48)
    int wbase = max(q0 + wave * 16 - 16, 0) - jlo_t;
    // zero P pad cols [48,64)
    {
        int pr = lane >> 2, c4 = (lane & 3) * 4;
        ushort4 z = {0, 0, 0, 0};
        *(ushort4*)&Ph[wave][pr * 72 + 48 + c4] = z;
        *(ushort4*)&Pl[wave][pr * 72 + 48 + c4] = z;
    }
    // NORMALIZED P -> windowed LDS, split hi/lo
#pragma unroll
    for (int nt = 0; nt < 6; ++nt) {
        int pcol = nt * 16 + col - wbase;
#pragma unroll
        for (int r = 0; r < 4; ++r) {
            if (pcol >= 0 && pcol < 48) {
                float pv = S[nt][r] * sum[r];
                unsigned short hi = f2bf(pv);
                Ph[wave][(quad * 4 + r) * 72 + pcol] = hi;
                Pl[wave][(quad * 4 + r) * 72 + pcol] = f2bf(pv - bf2f(hi));
            }
        }
    }
    __syncthreads();   // P + V pad writes visible before vector reloads
    // O = Ph.Vh + Pl.Vh + Ph.Vl over the 64-key window
    f32x4 O[4] = {};
#pragma unroll
    for (int ks = 0; ks < 64; ks += 32) {
        s16x8 aph = *(const s16x8*)&Ph[wave][col * 72 + ks + quad * 8];
        s16x8 apl = *(const s16x8*)&Pl[wave][col * 72 + ks + quad * 8];
#pragma unroll
        for (int nt = 0; nt < 4; ++nt) {
            s16x8 bvh = *(const s16x8*)&Vth[(nt * 16 + col) * 112 + wbase + ks + quad * 8];
            s16x8 bvl = *(const s16x8*)&Vtl[(nt * 16 + col) * 112 + wbase + ks + quad * 8];
            O[nt] = mfma_bf16(O[nt], aph, bvh);
            O[nt] = mfma_bf16(O[nt], apl, bvh);
            O[nt] = mfma_bf16(O[nt], aph, bvl);
        }
    }
    asm volatile("s_nop 7\ns_nop 7");
#pragma unroll
    for (int nt = 0; nt < 4; ++nt)
#pragma unroll
        for (int r = 0; r < 4; ++r) {
            int i = i_base + r;
            ctx[((size_t)(b << 10) + i) * 512 + h * 64 + nt * 16 + col] = f2bf(O[nt][r]);
        }
}

// ---------------- K6: out-proj GEMM staged + gated combine --------------------
__global__ __launch_bounds__(256) void k_out_combine(
        const unsigned short* __restrict__ Wt, const unsigned short* __restrict__ Actx,
        const float* __restrict__ bias, const float* __restrict__ xw,
        const float* __restrict__ sm, float* __restrict__ out) {
    __shared__ unsigned short As[128 * 64];
    __shared__ unsigned short Bs[128 * 64];
    int tid = threadIdx.x;
    int wave = tid >> 6, lane = tid & 63;
    int col = lane & 15, quad = lane >> 4;
    int wr = wave & 1, wc = wave >> 1;
    int mb = blockIdx.y * 128, nb = blockIdx.x * 128;
    int srow = tid >> 3, sko = tid & 7;
    f32x4 acc[4][4] = {};
    for (int kb = 0; kb < 512; kb += 64) {
#pragma unroll
        for (int p = 0; p < 4; ++p) {
            int r = p * 32 + srow;
            async_cp16(Wt + (size_t)(mb + r) * 512 + kb + sko * 8, &As[r * 64 + sko * 8]);
            async_cp16(Actx + (size_t)(nb + r) * 512 + kb + sko * 8, &Bs[r * 64 + sko * 8]);
        }
        __syncthreads();
#pragma unroll
        for (int ks = 0; ks < 64; ks += 32) {
            s16x8 a[4], b[4];
#pragma unroll
            for (int i = 0; i < 4; ++i)
                a[i] = *(const s16x8*)&As[(wr * 64 + i * 16 + col) * 64 + ks + quad * 8];
#pragma unroll
            for (int j = 0; j < 4; ++j)
                b[j] = *(const s16x8*)&Bs[(wc * 64 + j * 16 + col) * 64 + ks + quad * 8];
#pragma unroll
            for (int i = 0; i < 4; ++i)
#pragma unroll
                for (int j = 0; j < 4; ++j)
                    acc[i][j] = mfma_bf16(acc[i][j], a[i], b[j]);
        }
        __syncthreads();
    }
    asm volatile("s_nop 7\ns_nop 7");
#pragma unroll
    for (int i = 0; i < 4; ++i)
#pragma unroll
        for (int j = 0; j < 4; ++j) {
            int seq = nb + wc * 64 + j * 16 + col;
            int bb = seq >> 10, l = seq & 1023;
            float smv = sm[seq];
#pragma unroll
            for (int r = 0; r < 4; ++r) {
                int c = mb + wr * 64 + i * 16 + quad * 4 + r;
                float v = acc[i][j][r] + bias[c];
                size_t oidx = ((size_t)(bb * C_ + c) << 10) + l;
                out[oidx] = xw[oidx] + smv * v;
            }
        }
}

extern "C" void kernel_launch(void* const* d_in, const int* in_sizes, int n_in,
                              void* d_out, int out_size, void* d_ws, size_t ws_size,
                              hipStream_t stream) {
    const float* x      = (const float*)d_in[0];
    const float* dw_w   = (const float*)d_in[1];
    const float* dw_b   = (const float*)d_in[2];
    const float* sh_w   = (const float*)d_in[3];
    const float* sh_b   = (const float*)d_in[4];
    const float* mix_w  = (const float*)d_in[5];
    const float* bn_g   = (const float*)d_in[6];
    const float* bn_b   = (const float*)d_in[7];
    const float* det_w1 = (const float*)d_in[8];
    const float* det_b1 = (const float*)d_in[9];
    const float* det_w2 = (const float*)d_in[10];
    const float* det_b2 = (const float*)d_in[11];
    const float* inp_w  = (const float*)d_in[12];
    const float* inp_b  = (const float*)d_in[13];
    const float* outp_w = (const float*)d_in[14];
    const float* outp_b = (const float*)d_in[15];
    float* out = (float*)d_out;

    char* ws = (char*)d_ws;
    size_t off = 0;
    auto alloc = [&](size_t bytes) -> void* {
        void* p = ws + off;
        off += (bytes + 255) & ~(size_t)255;
        return p;
    };
    float* xw             = (float*)alloc((size_t)M_ * C_ * 4);
    unsigned short* comb  = (unsigned short*)alloc((size_t)M_ * 1024 * 2);
    unsigned short* qkvh  = (unsigned short*)alloc((size_t)M_ * 1536 * 2);
    unsigned short* qkvl  = (unsigned short*)alloc((size_t)M_ * 1536 * 2);
    unsigned short* ctx   = (unsigned short*)alloc((size_t)M_ * 512 * 2);
    float* smask          = (float*)alloc((size_t)M_ * 4);
    unsigned short* w1b   = (unsigned short*)alloc(131072 * 2);
    unsigned short* inwb  = (unsigned short*)alloc(786432 * 2);
    unsigned short* outwb = (unsigned short*)alloc(262144 * 2);
    (void)ws_size; (void)in_sizes; (void)n_in; (void)out_size;

    k_cvt_weights<<<3072, 256, 0, stream>>>(det_w1, inp_w, outp_w, w1b, inwb, outwb,
                                            131072, 786432, 262144);
    k_walze<<<B_ * C_, 256, 0, stream>>>(x, dw_w, dw_b, sh_w, sh_b, mix_w, bn_g, bn_b, xw);
    k_pack<<<dim3(16, 8, 8), 256, 0, stream>>>(x, xw, comb);
    k_detector<<<M_ / 16, 256, 0, stream>>>(comb, w1b, det_b1, det_w2, det_b2, smask);
    k_gemm_qkv<<<dim3(1536 / 128, M_ / 128), 256, 0, stream>>>(comb + 512, inwb, inp_b,
                                                               qkvh, qkvl);
    k_attn<<<dim3(16, NH_, B_), 256, 0, stream>>>(qkvh, qkvl, ctx);
    k_out_combine<<<dim3(M_ / 128, C_ / 128), 256, 0, stream>>>(outwb, ctx, outp_b,
                                                                xw, smask, out);
}

// Round 9
// 198.601 us; speedup vs baseline: 1.0201x; 1.0033x over previous
//
#include <hip/hip_runtime.h>

#define B_ 8
#define C_ 512
#define H_ 32
#define W_ 32
#define L_ 1024
#define M_ 8192   // B*L
#define NH_ 8
#define HD_ 64

typedef float f32x4 __attribute__((ext_vector_type(4)));
typedef short s16x8 __attribute__((ext_vector_type(8)));

// MFMA 16x16x32 bf16. C/D: col=lane&15 (n), row=(lane>>4)*4+reg (m).
// A frag: row m=lane&15, k=(lane>>4)*8+j ; B frag from B^T [n][k]: row n=lane&15.
__device__ __forceinline__ f32x4 mfma_bf16(f32x4 acc, s16x8 a, s16x8 b) {
    asm("v_mfma_f32_16x16x32_bf16 %0, %1, %2, %0" : "+v"(acc) : "v"(a), "v"(b));
    return acc;
}

__device__ __forceinline__ s16x8 ldg8(const unsigned short* p) {
    return *(const s16x8*)p;
}

typedef __attribute__((address_space(1))) const unsigned int glob_u32;
typedef __attribute__((address_space(3))) unsigned int lds_u32;
__device__ __forceinline__ void async_cp16(const void* g, void* l) {
    __builtin_amdgcn_global_load_lds((glob_u32*)g, (lds_u32*)l, 16, 0, 0);
}

__device__ __forceinline__ unsigned short f2bf(float f) {
    unsigned int u = __float_as_uint(f);
    unsigned int r = (u + 0x7FFFu + ((u >> 16) & 1u)) >> 16;
    return (unsigned short)r;
}

__device__ __forceinline__ float bf2f(unsigned short u) {
    return __uint_as_float(((unsigned int)u) << 16);
}

__device__ __forceinline__ float gelu_exact(float v) {
    return 0.5f * v * (1.0f + erff(v * 0.70710678118654752f));
}

__device__ __forceinline__ float sigmoidf_(float v) {
    return 1.0f / (1.0f + __expf(-v));
}

// ---------------- K0: fp32 -> bf16 weight conversion --------------------------
__global__ __launch_bounds__(256) void k_cvt_weights(
        const float* __restrict__ w1, const float* __restrict__ w2,
        const float* __restrict__ w3,
        unsigned short* __restrict__ o1, unsigned short* __restrict__ o2,
        unsigned short* __restrict__ o3, int n1, int n2, int n3) {
    int i = blockIdx.x * 256 + threadIdx.x;
    if (i < n1) o1[i] = f2bf(w1[i]);
    if (i < n2) o2[i] = f2bf(w2[i]);
    if (i < n3) o3[i] = f2bf(w3[i]);
}

// ---------------- K1: DualWalze (known-good) ----------------------------------
__global__ __launch_bounds__(256) void k_walze(
        const float* __restrict__ x, const float* __restrict__ dww,
        const float* __restrict__ dwb, const float* __restrict__ shw,
        const float* __restrict__ shb, const float* __restrict__ mixw,
        const float* __restrict__ gamma, const float* __restrict__ beta,
        float* __restrict__ xw) {
    __shared__ float tile[1024];
    int bc = blockIdx.x;           // b*C + c
    int c = bc & (C_ - 1);
    int tid = threadIdx.x;
    const float* xp = x + (size_t)bc * 1024;
#pragma unroll
    for (int t = 0; t < 4; ++t) tile[tid + 256 * t] = xp[tid + 256 * t];
    __syncthreads();
    float wm[9], wsh[9];
#pragma unroll
    for (int t = 0; t < 9; ++t) { wm[t] = dww[c * 9 + t]; wsh[t] = shw[t]; }
    float mix = sigmoidf_(mixw[0]);
    float bmain = dwb[c], bsh = shb[0];
    float g = gamma[c], bt = beta[c];
    const float rs = rsqrtf(1.0f + 1e-5f);
#pragma unroll
    for (int t = 0; t < 4; ++t) {
        int l = tid + 256 * t;
        int h = l >> 5, w = l & 31;
        float accm = 0.f, accs = 0.f;
#pragma unroll
        for (int kh = 0; kh < 3; ++kh) {
            int hh = (h + kh + 31) & 31;
#pragma unroll
            for (int kw = 0; kw < 3; ++kw) {
                int ww = (w + kw + 31) & 31;
                float v = tile[hh * 32 + ww];
                accm += v * wm[kh * 3 + kw];
                accs += v * wsh[kh * 3 + kw];
            }
        }
        float combined = mix * (accm + bmain) + (1.f - mix) * (accs + bsh) + tile[l];
        float bn = g * combined * rs + bt;
        xw[(size_t)bc * 1024 + l] = gelu_exact(bn);
    }
}

// ---------------- K2: LDS-tiled transpose+pack (known-good) -------------------
__global__ __launch_bounds__(256) void k_pack(
        const float* __restrict__ x, const float* __restrict__ xw,
        unsigned short* __restrict__ comb) {
    __shared__ float Tx[64 * 65];
    __shared__ float Tw[64 * 65];
    int b = blockIdx.z;
    int c0 = blockIdx.y * 64;
    int l0 = blockIdx.x * 64;
    int tid = threadIdx.x;
    for (int idx = tid; idx < 1024; idx += 256) {
        int cr = idx >> 4, f = idx & 15;
        size_t src = ((size_t)(b * C_ + c0 + cr) << 10) + l0 + f * 4;
        float4 vx = *(const float4*)(x + src);
        float4 vw = *(const float4*)(xw + src);
        *(float4*)&Tx[cr * 65 + f * 4] = vx;
        *(float4*)&Tw[cr * 65 + f * 4] = vw;
    }
    __syncthreads();
    for (int idx = tid; idx < 1024; idx += 256) {
        int lr = idx >> 4, f = idx & 15;
        ushort4 ux, uw;
        ux.x = f2bf(Tx[(4 * f + 0) * 65 + lr]);
        ux.y = f2bf(Tx[(4 * f + 1) * 65 + lr]);
        ux.z = f2bf(Tx[(4 * f + 2) * 65 + lr]);
        ux.w = f2bf(Tx[(4 * f + 3) * 65 + lr]);
        uw.x = f2bf(Tw[(4 * f + 0) * 65 + lr]);
        uw.y = f2bf(Tw[(4 * f + 1) * 65 + lr]);
        uw.z = f2bf(Tw[(4 * f + 2) * 65 + lr]);
        uw.w = f2bf(Tw[(4 * f + 3) * 65 + lr]);
        unsigned short* row = comb + (((size_t)(b << 10) + l0 + lr) << 10);
        *(ushort4*)(row + c0 + 4 * f) = ux;
        *(ushort4*)(row + 512 + c0 + 4 * f) = uw;
    }
}

// ---------------- K3: spike detector (known-good, 4-wave) ---------------------
__global__ __launch_bounds__(256) void k_detector(
        const unsigned short* __restrict__ comb, const unsigned short* __restrict__ w1,
        const float* __restrict__ b1, const float* __restrict__ w2,
        const float* __restrict__ b2, float* __restrict__ sm) {
    __shared__ float red[64];
    int tid = threadIdx.x;
    int wave = tid >> 6, lane = tid & 63;
    int col = lane & 15, quad = lane >> 4;
    int m0 = blockIdx.x * 16;
    int koff = quad * 8;
    int nb0 = wave * 32, nb1 = nb0 + 16;
    const unsigned short* pa  = comb + (size_t)(m0 + col) * 1024 + koff;
    const unsigned short* pw0 = w1 + (size_t)(nb0 + col) * 1024 + koff;
    const unsigned short* pw1 = w1 + (size_t)(nb1 + col) * 1024 + koff;
    f32x4 acc0 = {0.f, 0.f, 0.f, 0.f}, acc1 = {0.f, 0.f, 0.f, 0.f};
    for (int k = 0; k < 1024; k += 32) {
        s16x8 a = ldg8(pa + k);
        acc0 = mfma_bf16(acc0, a, ldg8(pw0 + k));
        acc1 = mfma_bf16(acc1, a, ldg8(pw1 + k));
    }
    asm volatile("s_nop 7\ns_nop 7");
    float bia0 = b1[nb0 + col], bia1 = b1[nb1 + col];
    float wv0 = w2[nb0 + col], wv1 = w2[nb1 + col];
#pragma unroll
    for (int r = 0; r < 4; ++r) {
        float h0 = gelu_exact(acc0[r] + bia0);
        float h1 = gelu_exact(acc1[r] + bia1);
        float p = h0 * wv0 + h1 * wv1;
        p += __shfl_xor(p, 1);
        p += __shfl_xor(p, 2);
        p += __shfl_xor(p, 4);
        p += __shfl_xor(p, 8);
        if (col == 0) red[wave * 16 + quad * 4 + r] = p;
    }
    __syncthreads();
    if (tid < 16) {
        float s = red[tid] + red[16 + tid] + red[32 + tid] + red[48 + tid] + b2[0];
        sm[m0 + tid] = sigmoidf_(s);
    }
}

// ---------------- K4: qkv GEMM, staged 128x128xBK64, split bf16 out -----------
__global__ __launch_bounds__(256) void k_gemm_qkv(
        const unsigned short* __restrict__ A,    // comb+512, lda=1024
        const unsigned short* __restrict__ Wt,   // [1536][512]
        const float* __restrict__ bias,
        unsigned short* __restrict__ out_hi, unsigned short* __restrict__ out_lo) {
    __shared__ unsigned short As[128 * 64];
    __shared__ unsigned short Bs[128 * 64];
    int tid = threadIdx.x;
    int wave = tid >> 6, lane = tid & 63;
    int col = lane & 15, quad = lane >> 4;
    int wr = wave & 1, wc = wave >> 1;
    int mb = blockIdx.y * 128, nb = blockIdx.x * 128;
    int srow = tid >> 3, sko = tid & 7;
    f32x4 acc[4][4] = {};
    for (int kb = 0; kb < 512; kb += 64) {
#pragma unroll
        for (int p = 0; p < 4; ++p) {
            int r = p * 32 + srow;
            async_cp16(A + (size_t)(mb + r) * 1024 + kb + sko * 8, &As[r * 64 + sko * 8]);
            async_cp16(Wt + (size_t)(nb + r) * 512 + kb + sko * 8, &Bs[r * 64 + sko * 8]);
        }
        __syncthreads();
#pragma unroll
        for (int ks = 0; ks < 64; ks += 32) {
            s16x8 a[4], b[4];
#pragma unroll
            for (int i = 0; i < 4; ++i)
                a[i] = *(const s16x8*)&As[(wr * 64 + i * 16 + col) * 64 + ks + quad * 8];
#pragma unroll
            for (int j = 0; j < 4; ++j)
                b[j] = *(const s16x8*)&Bs[(wc * 64 + j * 16 + col) * 64 + ks + quad * 8];
#pragma unroll
            for (int i = 0; i < 4; ++i)
#pragma unroll
                for (int j = 0; j < 4; ++j)
                    acc[i][j] = mfma_bf16(acc[i][j], a[i], b[j]);
        }
        __syncthreads();
    }
    asm volatile("s_nop 7\ns_nop 7");
#pragma unroll
    for (int i = 0; i < 4; ++i)
#pragma unroll
        for (int j = 0; j < 4; ++j) {
            int n = nb + wc * 64 + j * 16 + col;
            float bv = bias[n];
#pragma unroll
            for (int r = 0; r < 4; ++r) {
                int m = mb + wr * 64 + i * 16 + quad * 4 + r;
                float v = acc[i][j][r] + bv;
                unsigned short hi = f2bf(v);
                size_t idx = (size_t)m * 1536 + n;
                out_hi[idx] = hi;
                out_lo[idx] = f2bf(v - bf2f(hi));
            }
        }
}

// ---------------- K5: windowed attention via MFMA, split-precision ------------
// S = qh.kh + qh.kl + ql.kh over 96 staged keys; P NORMALIZED, split hi/lo into
// per-wave 48-key window buffers (16 pad cols zeroed); PV over K=64 window:
// O = Ph.Vh + Pl.Vh + Ph.Vl.
__global__ __launch_bounds__(256) void k_attn(
        const unsigned short* __restrict__ qkv_hi,
        const unsigned short* __restrict__ qkv_lo,
        unsigned short* __restrict__ ctx) {
    __shared__ unsigned short Vth[64 * 112];      // V hi [d][key], ld=112 (96 real + 16 zero pad)
    __shared__ unsigned short Vtl[64 * 112];      // V lo
    __shared__ unsigned short Ph[4][16 * 72];     // per-wave P hi [m][window-key], ld=72
    __shared__ unsigned short Pl[4][16 * 72];     // per-wave P lo
    int b = blockIdx.z, h = blockIdx.y;
    int q0 = blockIdx.x * 64;
    int tid = threadIdx.x, wave = tid >> 6, lane = tid & 63;
    int col = lane & 15, quad = lane >> 4;
    int jlo_t = max(q0 - 16, 0);
    const unsigned short* baseh = qkv_hi + ((size_t)(b << 10)) * 1536;
    const unsigned short* basel = qkv_lo + ((size_t)(b << 10)) * 1536;
    // stage V^T hi and lo: 12 key-groups x 64 d
#pragma unroll
    for (int it = 0; it < 3; ++it) {
        int slot = it * 256 + tid;
        int kg = slot >> 6, d = slot & 63;
        int key0 = jlo_t + kg * 8;
        unsigned short eh[8], el[8];
#pragma unroll
        for (int t = 0; t < 8; ++t) {
            size_t ro = (size_t)min(key0 + t, 1023) * 1536 + 1024 + h * 64 + d;
            eh[t] = baseh[ro];
            el[t] = basel[ro];
        }
        ushort4 h0 = {eh[0], eh[1], eh[2], eh[3]}, h1 = {eh[4], eh[5], eh[6], eh[7]};
        ushort4 l0 = {el[0], el[1], el[2], el[3]}, l1 = {el[4], el[5], el[6], el[7]};
        *(ushort4*)&Vth[d * 112 + kg * 8] = h0;
        *(ushort4*)&Vth[d * 112 + kg * 8 + 4] = h1;
        *(ushort4*)&Vtl[d * 112 + kg * 8] = l0;
        *(ushort4*)&Vtl[d * 112 + kg * 8 + 4] = l1;
    }
    // zero V pad keys [96,112)
    {
        int d = tid >> 2, c4 = (tid & 3) * 4;
        ushort4 z = {0, 0, 0, 0};
        *(ushort4*)&Vth[d * 112 + 96 + c4] = z;
        *(ushort4*)&Vtl[d * 112 + 96 + c4] = z;
    }
    __syncthreads();
    // Q A-frags hi+lo
    size_t qoff = (size_t)(q0 + wave * 16 + col) * 1536 + h * 64;
    s16x8 aq0h = ldg8(baseh + qoff + quad * 8);
    s16x8 aq1h = ldg8(baseh + qoff + 32 + quad * 8);
    s16x8 aq0l = ldg8(basel + qoff + quad * 8);
    s16x8 aq1l = ldg8(basel + qoff + 32 + quad * 8);
    // S over 6 key-tiles of 16
    f32x4 S[6];
#pragma unroll
    for (int nt = 0; nt < 6; ++nt) {
        size_t koffb = (size_t)min(jlo_t + nt * 16 + col, 1023) * 1536 + 512 + h * 64;
        s16x8 kh0 = ldg8(baseh + koffb + quad * 8);
        s16x8 kh1 = ldg8(baseh + koffb + 32 + quad * 8);
        s16x8 kl0 = ldg8(basel + koffb + quad * 8);
        s16x8 kl1 = ldg8(basel + koffb + 32 + quad * 8);
        f32x4 z = {0.f, 0.f, 0.f, 0.f};
        z = mfma_bf16(z, aq0h, kh0);
        z = mfma_bf16(z, aq1h, kh1);
        z = mfma_bf16(z, aq0h, kl0);
        z = mfma_bf16(z, aq1h, kl1);
        z = mfma_bf16(z, aq0l, kh0);
        z = mfma_bf16(z, aq1l, kh1);
        S[nt] = z;
    }
    asm volatile("s_nop 7\ns_nop 7");
    // masked softmax per row r
    int i_base = q0 + wave * 16 + quad * 4;
    float mx[4] = {-1e30f, -1e30f, -1e30f, -1e30f};
#pragma unroll
    for (int nt = 0; nt < 6; ++nt) {
        int j = jlo_t + nt * 16 + col;
#pragma unroll
        for (int r = 0; r < 4; ++r) {
            int i = i_base + r;
            bool ok = (j <= 1023) && (j >= i - 16) && (j <= i + 16);
            float s = ok ? S[nt][r] * 0.125f : -1e30f;
            S[nt][r] = s;
            mx[r] = fmaxf(mx[r], s);
        }
    }
#pragma unroll
    for (int r = 0; r < 4; ++r) {
        mx[r] = fmaxf(mx[r], __shfl_xor(mx[r], 1));
        mx[r] = fmaxf(mx[r], __shfl_xor(mx[r], 2));
        mx[r] = fmaxf(mx[r], __shfl_xor(mx[r], 4));
        mx[r] = fmaxf(mx[r], __shfl_xor(mx[r], 8));
    }
    float sum[4] = {0.f, 0.f, 0.f, 0.f};
#pragma unroll
    for (int nt = 0; nt < 6; ++nt)
#pragma unroll
        for (int r = 0; r < 4; ++r) {
            float p = __expf(S[nt][r] - mx[r]);
            S[nt][r] = p;
            sum[r] += p;
        }
#pragma unroll
    for (int r = 0; r < 4; ++r) {
        sum[r] += __shfl_xor(sum[r], 1);
        sum[r] += __shfl_xor(sum[r], 2);
        sum[r] += __shfl_xor(sum[r], 4);
        sum[r] += __shfl_xor(sum[r], 8);
        sum[r] = 1.f / sum[r];
    }
    // per-wave window base (block-relative); all nonzero P land in [0,48)
    int wbase = max(q0 + wave * 16 - 16, 0) - jlo_t;
    // zero P pad cols [48,64)
    {
        int pr = lane >> 2, c4 = (lane & 3) * 4;
        ushort4 z = {0, 0, 0, 0};
        *(ushort4*)&Ph[wave][pr * 72 + 48 + c4] = z;
        *(ushort4*)&Pl[wave][pr * 72 + 48 + c4] = z;
    }
    // NORMALIZED P -> windowed LDS, split hi/lo
#pragma unroll
    for (int nt = 0; nt < 6; ++nt) {
        int pcol = nt * 16 + col - wbase;
#pragma unroll
        for (int r = 0; r < 4; ++r) {
            if (pcol >= 0 && pcol < 48) {
                float pv = S[nt][r] * sum[r];
                unsigned short hi = f2bf(pv);
                Ph[wave][(quad * 4 + r) * 72 + pcol] = hi;
                Pl[wave][(quad * 4 + r) * 72 + pcol] = f2bf(pv - bf2f(hi));
            }
        }
    }
    __syncthreads();
    // O = Ph.Vh + Pl.Vh + Ph.Vl over the 64-key window
    f32x4 O[4] = {};
#pragma unroll
    for (int ks = 0; ks < 64; ks += 32) {
        s16x8 aph = *(const s16x8*)&Ph[wave][col * 72 + ks + quad * 8];
        s16x8 apl = *(const s16x8*)&Pl[wave][col * 72 + ks + quad * 8];
#pragma unroll
        for (int nt = 0; nt < 4; ++nt) {
            s16x8 bvh = *(const s16x8*)&Vth[(nt * 16 + col) * 112 + wbase + ks + quad * 8];
            s16x8 bvl = *(const s16x8*)&Vtl[(nt * 16 + col) * 112 + wbase + ks + quad * 8];
            O[nt] = mfma_bf16(O[nt], aph, bvh);
            O[nt] = mfma_bf16(O[nt], apl, bvh);
            O[nt] = mfma_bf16(O[nt], aph, bvl);
        }
    }
    asm volatile("s_nop 7\ns_nop 7");
#pragma unroll
    for (int nt = 0; nt < 4; ++nt)
#pragma unroll
        for (int r = 0; r < 4; ++r) {
            int i = i_base + r;
            ctx[((size_t)(b << 10) + i) * 512 + h * 64 + nt * 16 + col] = f2bf(O[nt][r]);
        }
}

// ---------------- K6: out-proj GEMM + gated combine, 64x64 tiles --------------
// Re-tiled 128x128 -> 64x64: grid (M_/64, C_/64) = 1024 blocks = 4 blocks/CU
// (was 256 = 1/CU: barrier drains fully exposed with no co-resident block).
__global__ __launch_bounds__(256) void k_out_combine(
        const unsigned short* __restrict__ Wt, const unsigned short* __restrict__ Actx,
        const float* __restrict__ bias, const float* __restrict__ xw,
        const float* __restrict__ sm, float* __restrict__ out) {
    __shared__ unsigned short As[64 * 64];
    __shared__ unsigned short Bs[64 * 64];
    int tid = threadIdx.x;
    int wave = tid >> 6, lane = tid & 63;
    int col = lane & 15, quad = lane >> 4;
    int wr = wave & 1, wc = wave >> 1;
    int mb = blockIdx.y * 64, nb = blockIdx.x * 64;
    int srow = tid >> 3, sko = tid & 7;     // lane-linear LDS dest (l*16B) per wave
    f32x4 acc[2][2] = {};
    for (int kb = 0; kb < 512; kb += 64) {
#pragma unroll
        for (int p = 0; p < 2; ++p) {
            int r = p * 32 + srow;
            async_cp16(Wt + (size_t)(mb + r) * 512 + kb + sko * 8, &As[r * 64 + sko * 8]);
            async_cp16(Actx + (size_t)(nb + r) * 512 + kb + sko * 8, &Bs[r * 64 + sko * 8]);
        }
        __syncthreads();
#pragma unroll
        for (int ks = 0; ks < 64; ks += 32) {
            s16x8 a[2], b[2];
#pragma unroll
            for (int i = 0; i < 2; ++i)
                a[i] = *(const s16x8*)&As[(wr * 32 + i * 16 + col) * 64 + ks + quad * 8];
#pragma unroll
            for (int j = 0; j < 2; ++j)
                b[j] = *(const s16x8*)&Bs[(wc * 32 + j * 16 + col) * 64 + ks + quad * 8];
#pragma unroll
            for (int i = 0; i < 2; ++i)
#pragma unroll
                for (int j = 0; j < 2; ++j)
                    acc[i][j] = mfma_bf16(acc[i][j], a[i], b[j]);
        }
        __syncthreads();
    }
    asm volatile("s_nop 7\ns_nop 7");
#pragma unroll
    for (int i = 0; i < 2; ++i)
#pragma unroll
        for (int j = 0; j < 2; ++j) {
            int seq = nb + wc * 32 + j * 16 + col;
            int bb = seq >> 10, l = seq & 1023;
            float smv = sm[seq];
#pragma unroll
            for (int r = 0; r < 4; ++r) {
                int c = mb + wr * 32 + i * 16 + quad * 4 + r;
                float v = acc[i][j][r] + bias[c];
                size_t oidx = ((size_t)(bb * C_ + c) << 10) + l;
                out[oidx] = xw[oidx] + smv * v;
            }
        }
}

extern "C" void kernel_launch(void* const* d_in, const int* in_sizes, int n_in,
                              void* d_out, int out_size, void* d_ws, size_t ws_size,
                              hipStream_t stream) {
    const float* x      = (const float*)d_in[0];
    const float* dw_w   = (const float*)d_in[1];
    const float* dw_b   = (const float*)d_in[2];
    const float* sh_w   = (const float*)d_in[3];
    const float* sh_b   = (const float*)d_in[4];
    const float* mix_w  = (const float*)d_in[5];
    const float* bn_g   = (const float*)d_in[6];
    const float* bn_b   = (const float*)d_in[7];
    const float* det_w1 = (const float*)d_in[8];
    const float* det_b1 = (const float*)d_in[9];
    const float* det_w2 = (const float*)d_in[10];
    const float* det_b2 = (const float*)d_in[11];
    const float* inp_w  = (const float*)d_in[12];
    const float* inp_b  = (const float*)d_in[13];
    const float* outp_w = (const float*)d_in[14];
    const float* outp_b = (const float*)d_in[15];
    float* out = (float*)d_out;

    char* ws = (char*)d_ws;
    size_t off = 0;
    auto alloc = [&](size_t bytes) -> void* {
        void* p = ws + off;
        off += (bytes + 255) & ~(size_t)255;
        return p;
    };
    float* xw             = (float*)alloc((size_t)M_ * C_ * 4);
    unsigned short* comb  = (unsigned short*)alloc((size_t)M_ * 1024 * 2);
    unsigned short* qkvh  = (unsigned short*)alloc((size_t)M_ * 1536 * 2);
    unsigned short* qkvl  = (unsigned short*)alloc((size_t)M_ * 1536 * 2);
    unsigned short* ctx   = (unsigned short*)alloc((size_t)M_ * 512 * 2);
    float* smask          = (float*)alloc((size_t)M_ * 4);
    unsigned short* w1b   = (unsigned short*)alloc(131072 * 2);
    unsigned short* inwb  = (unsigned short*)alloc(786432 * 2);
    unsigned short* outwb = (unsigned short*)alloc(262144 * 2);
    (void)ws_size; (void)in_sizes; (void)n_in; (void)out_size;

    k_cvt_weights<<<3072, 256, 0, stream>>>(det_w1, inp_w, outp_w, w1b, inwb, outwb,
                                            131072, 786432, 262144);
    k_walze<<<B_ * C_, 256, 0, stream>>>(x, dw_w, dw_b, sh_w, sh_b, mix_w, bn_g, bn_b, xw);
    k_pack<<<dim3(16, 8, 8), 256, 0, stream>>>(x, xw, comb);
    k_detector<<<M_ / 16, 256, 0, stream>>>(comb, w1b, det_b1, det_w2, det_b2, smask);
    k_gemm_qkv<<<dim3(1536 / 128, M_ / 128), 256, 0, stream>>>(comb + 512, inwb, inp_b,
                                                               qkvh, qkvl);
    k_attn<<<dim3(16, NH_, B_), 256, 0, stream>>>(qkvh, qkvl, ctx);
    k_out_combine<<<dim3(M_ / 64, C_ / 64), 256, 0, stream>>>(outwb, ctx, outp_b,
                                                              xw, smask, out);
}

// Round 10
// 192.760 us; speedup vs baseline: 1.0510x; 1.0303x over previous
//
#include <hip/hip_runtime.h>

#define B_ 8
#define C_ 512
#define H_ 32
#define W_ 32
#define L_ 1024
#define M_ 8192   // B*L
#define NH_ 8
#define HD_ 64

typedef float f32x4 __attribute__((ext_vector_type(4)));
typedef short s16x8 __attribute__((ext_vector_type(8)));

// MFMA 16x16x32 bf16. C/D: col=lane&15 (n), row=(lane>>4)*4+reg (m).
// A frag: row m=lane&15, k=(lane>>4)*8+j ; B frag from B^T [n][k]: row n=lane&15.
__device__ __forceinline__ f32x4 mfma_bf16(f32x4 acc, s16x8 a, s16x8 b) {
    asm("v_mfma_f32_16x16x32_bf16 %0, %1, %2, %0" : "+v"(acc) : "v"(a), "v"(b));
    return acc;
}

__device__ __forceinline__ s16x8 ldg8(const unsigned short* p) {
    return *(const s16x8*)p;
}

typedef __attribute__((address_space(1))) const unsigned int glob_u32;
typedef __attribute__((address_space(3))) unsigned int lds_u32;
__device__ __forceinline__ void async_cp16(const void* g, void* l) {
    __builtin_amdgcn_global_load_lds((glob_u32*)g, (lds_u32*)l, 16, 0, 0);
}

__device__ __forceinline__ unsigned short f2bf(float f) {
    unsigned int u = __float_as_uint(f);
    unsigned int r = (u + 0x7FFFu + ((u >> 16) & 1u)) >> 16;
    return (unsigned short)r;
}

__device__ __forceinline__ float bf2f(unsigned short u) {
    return __uint_as_float(((unsigned int)u) << 16);
}

__device__ __forceinline__ float gelu_exact(float v) {
    return 0.5f * v * (1.0f + erff(v * 0.70710678118654752f));
}

__device__ __forceinline__ float sigmoidf_(float v) {
    return 1.0f / (1.0f + __expf(-v));
}

// ---------------- K0: fp32 -> bf16 weight conversion --------------------------
__global__ __launch_bounds__(256) void k_cvt_weights(
        const float* __restrict__ w1, const float* __restrict__ w2,
        const float* __restrict__ w3,
        unsigned short* __restrict__ o1, unsigned short* __restrict__ o2,
        unsigned short* __restrict__ o3, int n1, int n2, int n3) {
    int i = blockIdx.x * 256 + threadIdx.x;
    if (i < n1) o1[i] = f2bf(w1[i]);
    if (i < n2) o2[i] = f2bf(w2[i]);
    if (i < n3) o3[i] = f2bf(w3[i]);
}

// ---------------- K1: DualWalze (known-good) ----------------------------------
__global__ __launch_bounds__(256) void k_walze(
        const float* __restrict__ x, const float* __restrict__ dww,
        const float* __restrict__ dwb, const float* __restrict__ shw,
        const float* __restrict__ shb, const float* __restrict__ mixw,
        const float* __restrict__ gamma, const float* __restrict__ beta,
        float* __restrict__ xw) {
    __shared__ float tile[1024];
    int bc = blockIdx.x;           // b*C + c
    int c = bc & (C_ - 1);
    int tid = threadIdx.x;
    const float* xp = x + (size_t)bc * 1024;
#pragma unroll
    for (int t = 0; t < 4; ++t) tile[tid + 256 * t] = xp[tid + 256 * t];
    __syncthreads();
    float wm[9], wsh[9];
#pragma unroll
    for (int t = 0; t < 9; ++t) { wm[t] = dww[c * 9 + t]; wsh[t] = shw[t]; }
    float mix = sigmoidf_(mixw[0]);
    float bmain = dwb[c], bsh = shb[0];
    float g = gamma[c], bt = beta[c];
    const float rs = rsqrtf(1.0f + 1e-5f);
#pragma unroll
    for (int t = 0; t < 4; ++t) {
        int l = tid + 256 * t;
        int h = l >> 5, w = l & 31;
        float accm = 0.f, accs = 0.f;
#pragma unroll
        for (int kh = 0; kh < 3; ++kh) {
            int hh = (h + kh + 31) & 31;
#pragma unroll
            for (int kw = 0; kw < 3; ++kw) {
                int ww = (w + kw + 31) & 31;
                float v = tile[hh * 32 + ww];
                accm += v * wm[kh * 3 + kw];
                accs += v * wsh[kh * 3 + kw];
            }
        }
        float combined = mix * (accm + bmain) + (1.f - mix) * (accs + bsh) + tile[l];
        float bn = g * combined * rs + bt;
        xw[(size_t)bc * 1024 + l] = gelu_exact(bn);
    }
}

// ---------------- K2: LDS-tiled transpose+pack (known-good) -------------------
__global__ __launch_bounds__(256) void k_pack(
        const float* __restrict__ x, const float* __restrict__ xw,
        unsigned short* __restrict__ comb) {
    __shared__ float Tx[64 * 65];
    __shared__ float Tw[64 * 65];
    int b = blockIdx.z;
    int c0 = blockIdx.y * 64;
    int l0 = blockIdx.x * 64;
    int tid = threadIdx.x;
    for (int idx = tid; idx < 1024; idx += 256) {
        int cr = idx >> 4, f = idx & 15;
        size_t src = ((size_t)(b * C_ + c0 + cr) << 10) + l0 + f * 4;
        float4 vx = *(const float4*)(x + src);
        float4 vw = *(const float4*)(xw + src);
        *(float4*)&Tx[cr * 65 + f * 4] = vx;
        *(float4*)&Tw[cr * 65 + f * 4] = vw;
    }
    __syncthreads();
    for (int idx = tid; idx < 1024; idx += 256) {
        int lr = idx >> 4, f = idx & 15;
        ushort4 ux, uw;
        ux.x = f2bf(Tx[(4 * f + 0) * 65 + lr]);
        ux.y = f2bf(Tx[(4 * f + 1) * 65 + lr]);
        ux.z = f2bf(Tx[(4 * f + 2) * 65 + lr]);
        ux.w = f2bf(Tx[(4 * f + 3) * 65 + lr]);
        uw.x = f2bf(Tw[(4 * f + 0) * 65 + lr]);
        uw.y = f2bf(Tw[(4 * f + 1) * 65 + lr]);
        uw.z = f2bf(Tw[(4 * f + 2) * 65 + lr]);
        uw.w = f2bf(Tw[(4 * f + 3) * 65 + lr]);
        unsigned short* row = comb + (((size_t)(b << 10) + l0 + lr) << 10);
        *(ushort4*)(row + c0 + 4 * f) = ux;
        *(ushort4*)(row + 512 + c0 + 4 * f) = uw;
    }
}

// ---------------- K3: spike detector (known-good, 4-wave) ---------------------
__global__ __launch_bounds__(256) void k_detector(
        const unsigned short* __restrict__ comb, const unsigned short* __restrict__ w1,
        const float* __restrict__ b1, const float* __restrict__ w2,
        const float* __restrict__ b2, float* __restrict__ sm) {
    __shared__ float red[64];
    int tid = threadIdx.x;
    int wave = tid >> 6, lane = tid & 63;
    int col = lane & 15, quad = lane >> 4;
    int m0 = blockIdx.x * 16;
    int koff = quad * 8;
    int nb0 = wave * 32, nb1 = nb0 + 16;
    const unsigned short* pa  = comb + (size_t)(m0 + col) * 1024 + koff;
    const unsigned short* pw0 = w1 + (size_t)(nb0 + col) * 1024 + koff;
    const unsigned short* pw1 = w1 + (size_t)(nb1 + col) * 1024 + koff;
    f32x4 acc0 = {0.f, 0.f, 0.f, 0.f}, acc1 = {0.f, 0.f, 0.f, 0.f};
    for (int k = 0; k < 1024; k += 32) {
        s16x8 a = ldg8(pa + k);
        acc0 = mfma_bf16(acc0, a, ldg8(pw0 + k));
        acc1 = mfma_bf16(acc1, a, ldg8(pw1 + k));
    }
    asm volatile("s_nop 7\ns_nop 7");
    float bia0 = b1[nb0 + col], bia1 = b1[nb1 + col];
    float wv0 = w2[nb0 + col], wv1 = w2[nb1 + col];
#pragma unroll
    for (int r = 0; r < 4; ++r) {
        float h0 = gelu_exact(acc0[r] + bia0);
        float h1 = gelu_exact(acc1[r] + bia1);
        float p = h0 * wv0 + h1 * wv1;
        p += __shfl_xor(p, 1);
        p += __shfl_xor(p, 2);
        p += __shfl_xor(p, 4);
        p += __shfl_xor(p, 8);
        if (col == 0) red[wave * 16 + quad * 4 + r] = p;
    }
    __syncthreads();
    if (tid < 16) {
        float s = red[tid] + red[16 + tid] + red[32 + tid] + red[48 + tid] + b2[0];
        sm[m0 + tid] = sigmoidf_(s);
    }
}

// ---------------- K4: qkv GEMM, staged 128x128xBK64, split bf16 out -----------
__global__ __launch_bounds__(256) void k_gemm_qkv(
        const unsigned short* __restrict__ A,    // comb+512, lda=1024
        const unsigned short* __restrict__ Wt,   // [1536][512]
        const float* __restrict__ bias,
        unsigned short* __restrict__ out_hi, unsigned short* __restrict__ out_lo) {
    __shared__ unsigned short As[128 * 64];
    __shared__ unsigned short Bs[128 * 64];
    int tid = threadIdx.x;
    int wave = tid >> 6, lane = tid & 63;
    int col = lane & 15, quad = lane >> 4;
    int wr = wave & 1, wc = wave >> 1;
    int mb = blockIdx.y * 128, nb = blockIdx.x * 128;
    int srow = tid >> 3, sko = tid & 7;
    f32x4 acc[4][4] = {};
    for (int kb = 0; kb < 512; kb += 64) {
#pragma unroll
        for (int p = 0; p < 4; ++p) {
            int r = p * 32 + srow;
            async_cp16(A + (size_t)(mb + r) * 1024 + kb + sko * 8, &As[r * 64 + sko * 8]);
            async_cp16(Wt + (size_t)(nb + r) * 512 + kb + sko * 8, &Bs[r * 64 + sko * 8]);
        }
        __syncthreads();
#pragma unroll
        for (int ks = 0; ks < 64; ks += 32) {
            s16x8 a[4], b[4];
#pragma unroll
            for (int i = 0; i < 4; ++i)
                a[i] = *(const s16x8*)&As[(wr * 64 + i * 16 + col) * 64 + ks + quad * 8];
#pragma unroll
            for (int j = 0; j < 4; ++j)
                b[j] = *(const s16x8*)&Bs[(wc * 64 + j * 16 + col) * 64 + ks + quad * 8];
#pragma unroll
            for (int i = 0; i < 4; ++i)
#pragma unroll
                for (int j = 0; j < 4; ++j)
                    acc[i][j] = mfma_bf16(acc[i][j], a[i], b[j]);
        }
        __syncthreads();
    }
    asm volatile("s_nop 7\ns_nop 7");
#pragma unroll
    for (int i = 0; i < 4; ++i)
#pragma unroll
        for (int j = 0; j < 4; ++j) {
            int n = nb + wc * 64 + j * 16 + col;
            float bv = bias[n];
#pragma unroll
            for (int r = 0; r < 4; ++r) {
                int m = mb + wr * 64 + i * 16 + quad * 4 + r;
                float v = acc[i][j][r] + bv;
                unsigned short hi = f2bf(v);
                size_t idx = (size_t)m * 1536 + n;
                out_hi[idx] = hi;
                out_lo[idx] = f2bf(v - bf2f(hi));
            }
        }
}

// ---------------- K5: windowed attention via MFMA, split-precision ------------
// NEW: S phase runs only the <=3 live key-tiles per wave (window = 48 keys);
// dead tiles (fully masked) are skipped: K loads 24->12/lane, S-MFMA 36->18,
// exp 24->12. P layout: pcol = u*16+col in [0,48) exactly; [48,64) pad zeroed.
// PV over K=64 window unchanged: O = Ph.Vh + Pl.Vh + Ph.Vl.
__global__ __launch_bounds__(256) void k_attn(
        const unsigned short* __restrict__ qkv_hi,
        const unsigned short* __restrict__ qkv_lo,
        unsigned short* __restrict__ ctx) {
    __shared__ unsigned short Vth[64 * 112];      // V hi [d][key], ld=112 (96 real + 16 zero pad)
    __shared__ unsigned short Vtl[64 * 112];      // V lo
    __shared__ unsigned short Ph[4][16 * 72];     // per-wave P hi [m][window-key], ld=72
    __shared__ unsigned short Pl[4][16 * 72];     // per-wave P lo
    int b = blockIdx.z, h = blockIdx.y;
    int q0 = blockIdx.x * 64;
    int tid = threadIdx.x, wave = tid >> 6, lane = tid & 63;
    int col = lane & 15, quad = lane >> 4;
    int jlo_t = max(q0 - 16, 0);
    const unsigned short* baseh = qkv_hi + ((size_t)(b << 10)) * 1536;
    const unsigned short* basel = qkv_lo + ((size_t)(b << 10)) * 1536;
    // stage V^T hi and lo: 12 key-groups x 64 d
#pragma unroll
    for (int it = 0; it < 3; ++it) {
        int slot = it * 256 + tid;
        int kg = slot >> 6, d = slot & 63;
        int key0 = jlo_t + kg * 8;
        unsigned short eh[8], el[8];
#pragma unroll
        for (int t = 0; t < 8; ++t) {
            size_t ro = (size_t)min(key0 + t, 1023) * 1536 + 1024 + h * 64 + d;
            eh[t] = baseh[ro];
            el[t] = basel[ro];
        }
        ushort4 h0 = {eh[0], eh[1], eh[2], eh[3]}, h1 = {eh[4], eh[5], eh[6], eh[7]};
        ushort4 l0 = {el[0], el[1], el[2], el[3]}, l1 = {el[4], el[5], el[6], el[7]};
        *(ushort4*)&Vth[d * 112 + kg * 8] = h0;
        *(ushort4*)&Vth[d * 112 + kg * 8 + 4] = h1;
        *(ushort4*)&Vtl[d * 112 + kg * 8] = l0;
        *(ushort4*)&Vtl[d * 112 + kg * 8 + 4] = l1;
    }
    // zero V pad keys [96,112)
    {
        int d = tid >> 2, c4 = (tid & 3) * 4;
        ushort4 z = {0, 0, 0, 0};
        *(ushort4*)&Vth[d * 112 + 96 + c4] = z;
        *(ushort4*)&Vtl[d * 112 + 96 + c4] = z;
    }
    __syncthreads();
    // Q A-frags hi+lo
    int i_min = q0 + wave * 16;
    size_t qoff = (size_t)(i_min + col) * 1536 + h * 64;
    s16x8 aq0h = ldg8(baseh + qoff + quad * 8);
    s16x8 aq1h = ldg8(baseh + qoff + 32 + quad * 8);
    s16x8 aq0l = ldg8(basel + qoff + quad * 8);
    s16x8 aq1l = ldg8(basel + qoff + 32 + quad * 8);
    // live key-tile range for this wave (wave-uniform, <=3 tiles)
    int t0 = (max(i_min - 16, 0) - jlo_t) >> 4;
    int t1 = (min(i_min + 31, 1023) - jlo_t) >> 4;
    // S over live tiles only
    f32x4 S[3];
#pragma unroll
    for (int u = 0; u < 3; ++u) {
        int nt = t0 + u;
        size_t koffb = (size_t)min(jlo_t + nt * 16 + col, 1023) * 1536 + 512 + h * 64;
        s16x8 kh0 = ldg8(baseh + koffb + quad * 8);
        s16x8 kh1 = ldg8(baseh + koffb + 32 + quad * 8);
        s16x8 kl0 = ldg8(basel + koffb + quad * 8);
        s16x8 kl1 = ldg8(basel + koffb + 32 + quad * 8);
        f32x4 z = {0.f, 0.f, 0.f, 0.f};
        z = mfma_bf16(z, aq0h, kh0);
        z = mfma_bf16(z, aq1h, kh1);
        z = mfma_bf16(z, aq0h, kl0);
        z = mfma_bf16(z, aq1h, kl1);
        z = mfma_bf16(z, aq0l, kh0);
        z = mfma_bf16(z, aq1l, kh1);
        S[u] = z;
    }
    asm volatile("s_nop 7\ns_nop 7");
    // masked softmax per row r
    int i_base = i_min + quad * 4;
    float mx[4] = {-1e30f, -1e30f, -1e30f, -1e30f};
#pragma unroll
    for (int u = 0; u < 3; ++u) {
        int nt = t0 + u;
        int j = jlo_t + nt * 16 + col;
        bool live = (nt <= t1);
#pragma unroll
        for (int r = 0; r < 4; ++r) {
            int i = i_base + r;
            bool ok = live && (j <= 1023) && (j >= i - 16) && (j <= i + 16);
            float s = ok ? S[u][r] * 0.125f : -1e30f;
            S[u][r] = s;
            mx[r] = fmaxf(mx[r], s);
        }
    }
#pragma unroll
    for (int r = 0; r < 4; ++r) {
        mx[r] = fmaxf(mx[r], __shfl_xor(mx[r], 1));
        mx[r] = fmaxf(mx[r], __shfl_xor(mx[r], 2));
        mx[r] = fmaxf(mx[r], __shfl_xor(mx[r], 4));
        mx[r] = fmaxf(mx[r], __shfl_xor(mx[r], 8));
    }
    float sum[4] = {0.f, 0.f, 0.f, 0.f};
#pragma unroll
    for (int u = 0; u < 3; ++u)
#pragma unroll
        for (int r = 0; r < 4; ++r) {
            float p = __expf(S[u][r] - mx[r]);   // masked -> 0
            S[u][r] = p;
            sum[r] += p;
        }
#pragma unroll
    for (int r = 0; r < 4; ++r) {
        sum[r] += __shfl_xor(sum[r], 1);
        sum[r] += __shfl_xor(sum[r], 2);
        sum[r] += __shfl_xor(sum[r], 4);
        sum[r] += __shfl_xor(sum[r], 8);
        sum[r] = 1.f / sum[r];
    }
    int wbase = t0 * 16;                     // window base within staged keys
    // zero P pad cols [48,64)
    {
        int pr = lane >> 2, c4 = (lane & 3) * 4;
        ushort4 z = {0, 0, 0, 0};
        *(ushort4*)&Ph[wave][pr * 72 + 48 + c4] = z;
        *(ushort4*)&Pl[wave][pr * 72 + 48 + c4] = z;
    }
    // NORMALIZED P -> windowed LDS, split hi/lo (pcol = u*16+col covers [0,48))
#pragma unroll
    for (int u = 0; u < 3; ++u) {
        int pcol = u * 16 + col;
#pragma unroll
        for (int r = 0; r < 4; ++r) {
            float pv = S[u][r] * sum[r];     // 0 for dead tiles
            unsigned short hi = f2bf(pv);
            Ph[wave][(quad * 4 + r) * 72 + pcol] = hi;
            Pl[wave][(quad * 4 + r) * 72 + pcol] = f2bf(pv - bf2f(hi));
        }
    }
    __syncthreads();
    // O = Ph.Vh + Pl.Vh + Ph.Vl over the 64-key window
    f32x4 O[4] = {};
#pragma unroll
    for (int ks = 0; ks < 64; ks += 32) {
        s16x8 aph = *(const s16x8*)&Ph[wave][col * 72 + ks + quad * 8];
        s16x8 apl = *(const s16x8*)&Pl[wave][col * 72 + ks + quad * 8];
#pragma unroll
        for (int nt = 0; nt < 4; ++nt) {
            s16x8 bvh = *(const s16x8*)&Vth[(nt * 16 + col) * 112 + wbase + ks + quad * 8];
            s16x8 bvl = *(const s16x8*)&Vtl[(nt * 16 + col) * 112 + wbase + ks + quad * 8];
            O[nt] = mfma_bf16(O[nt], aph, bvh);
            O[nt] = mfma_bf16(O[nt], apl, bvh);
            O[nt] = mfma_bf16(O[nt], aph, bvl);
        }
    }
    asm volatile("s_nop 7\ns_nop 7");
#pragma unroll
    for (int nt = 0; nt < 4; ++nt)
#pragma unroll
        for (int r = 0; r < 4; ++r) {
            int i = i_base + r;
            ctx[((size_t)(b << 10) + i) * 512 + h * 64 + nt * 16 + col] = f2bf(O[nt][r]);
        }
}

// ---------------- K6: out-proj GEMM + gated combine, 64x64 tiles --------------
__global__ __launch_bounds__(256) void k_out_combine(
        const unsigned short* __restrict__ Wt, const unsigned short* __restrict__ Actx,
        const float* __restrict__ bias, const float* __restrict__ xw,
        const float* __restrict__ sm, float* __restrict__ out) {
    __shared__ unsigned short As[64 * 64];
    __shared__ unsigned short Bs[64 * 64];
    int tid = threadIdx.x;
    int wave = tid >> 6, lane = tid & 63;
    int col = lane & 15, quad = lane >> 4;
    int wr = wave & 1, wc = wave >> 1;
    int mb = blockIdx.y * 64, nb = blockIdx.x * 64;
    int srow = tid >> 3, sko = tid & 7;
    f32x4 acc[2][2] = {};
    for (int kb = 0; kb < 512; kb += 64) {
#pragma unroll
        for (int p = 0; p < 2; ++p) {
            int r = p * 32 + srow;
            async_cp16(Wt + (size_t)(mb + r) * 512 + kb + sko * 8, &As[r * 64 + sko * 8]);
            async_cp16(Actx + (size_t)(nb + r) * 512 + kb + sko * 8, &Bs[r * 64 + sko * 8]);
        }
        __syncthreads();
#pragma unroll
        for (int ks = 0; ks < 64; ks += 32) {
            s16x8 a[2], b[2];
#pragma unroll
            for (int i = 0; i < 2; ++i)
                a[i] = *(const s16x8*)&As[(wr * 32 + i * 16 + col) * 64 + ks + quad * 8];
#pragma unroll
            for (int j = 0; j < 2; ++j)
                b[j] = *(const s16x8*)&Bs[(wc * 32 + j * 16 + col) * 64 + ks + quad * 8];
#pragma unroll
            for (int i = 0; i < 2; ++i)
#pragma unroll
                for (int j = 0; j < 2; ++j)
                    acc[i][j] = mfma_bf16(acc[i][j], a[i], b[j]);
        }
        __syncthreads();
    }
    asm volatile("s_nop 7\ns_nop 7");
#pragma unroll
    for (int i = 0; i < 2; ++i)
#pragma unroll
        for (int j = 0; j < 2; ++j) {
            int seq = nb + wc * 32 + j * 16 + col;
            int bb = seq >> 10, l = seq & 1023;
            float smv = sm[seq];
#pragma unroll
            for (int r = 0; r < 4; ++r) {
                int c = mb + wr * 32 + i * 16 + quad * 4 + r;
                float v = acc[i][j][r] + bias[c];
                size_t oidx = ((size_t)(bb * C_ + c) << 10) + l;
                out[oidx] = xw[oidx] + smv * v;
            }
        }
}

extern "C" void kernel_launch(void* const* d_in, const int* in_sizes, int n_in,
                              void* d_out, int out_size, void* d_ws, size_t ws_size,
                              hipStream_t stream) {
    const float* x      = (const float*)d_in[0];
    const float* dw_w   = (const float*)d_in[1];
    const float* dw_b   = (const float*)d_in[2];
    const float* sh_w   = (const float*)d_in[3];
    const float* sh_b   = (const float*)d_in[4];
    const float* mix_w  = (const float*)d_in[5];
    const float* bn_g   = (const float*)d_in[6];
    const float* bn_b   = (const float*)d_in[7];
    const float* det_w1 = (const float*)d_in[8];
    const float* det_b1 = (const float*)d_in[9];
    const float* det_w2 = (const float*)d_in[10];
    const float* det_b2 = (const float*)d_in[11];
    const float* inp_w  = (const float*)d_in[12];
    const float* inp_b  = (const float*)d_in[13];
    const float* outp_w = (const float*)d_in[14];
    const float* outp_b = (const float*)d_in[15];
    float* out = (float*)d_out;

    char* ws = (char*)d_ws;
    size_t off = 0;
    auto alloc = [&](size_t bytes) -> void* {
        void* p = ws + off;
        off += (bytes + 255) & ~(size_t)255;
        return p;
    };
    float* xw             = (float*)alloc((size_t)M_ * C_ * 4);
    unsigned short* comb  = (unsigned short*)alloc((size_t)M_ * 1024 * 2);
    unsigned short* qkvh  = (unsigned short*)alloc((size_t)M_ * 1536 * 2);
    unsigned short* qkvl  = (unsigned short*)alloc((size_t)M_ * 1536 * 2);
    unsigned short* ctx   = (unsigned short*)alloc((size_t)M_ * 512 * 2);
    float* smask          = (float*)alloc((size_t)M_ * 4);
    unsigned short* w1b   = (unsigned short*)alloc(131072 * 2);
    unsigned short* inwb  = (unsigned short*)alloc(786432 * 2);
    unsigned short* outwb = (unsigned short*)alloc(262144 * 2);
    (void)ws_size; (void)in_sizes; (void)n_in; (void)out_size;

    k_cvt_weights<<<3072, 256, 0, stream>>>(det_w1, inp_w, outp_w, w1b, inwb, outwb,
                                            131072, 786432, 262144);
    k_walze<<<B_ * C_, 256, 0, stream>>>(x, dw_w, dw_b, sh_w, sh_b, mix_w, bn_g, bn_b, xw);
    k_pack<<<dim3(16, 8, 8), 256, 0, stream>>>(x, xw, comb);
    k_detector<<<M_ / 16, 256, 0, stream>>>(comb, w1b, det_b1, det_w2, det_b2, smask);
    k_gemm_qkv<<<dim3(1536 / 128, M_ / 128), 256, 0, stream>>>(comb + 512, inwb, inp_b,
                                                               qkvh, qkvl);
    k_attn<<<dim3(16, NH_, B_), 256, 0, stream>>>(qkvh, qkvl, ctx);
    k_out_combine<<<dim3(M_ / 64, C_ / 64), 256, 0, stream>>>(outwb, ctx, outp_b,
                                                              xw, smask, out);
}

// Round 11
// 187.203 us; speedup vs baseline: 1.0822x; 1.0297x over previous
//
#include <hip/hip_runtime.h>

#define B_ 8
#define C_ 512
#define H_ 32
#define W_ 32
#define L_ 1024
#define M_ 8192   // B*L
#define NH_ 8
#define HD_ 64

typedef float f32x4 __attribute__((ext_vector_type(4)));
typedef short s16x8 __attribute__((ext_vector_type(8)));

// MFMA 16x16x32 bf16. C/D: col=lane&15 (n), row=(lane>>4)*4+reg (m).
// A frag: row m=lane&15, k=(lane>>4)*8+j ; B frag from B^T [n][k]: row n=lane&15.
__device__ __forceinline__ f32x4 mfma_bf16(f32x4 acc, s16x8 a, s16x8 b) {
    asm("v_mfma_f32_16x16x32_bf16 %0, %1, %2, %0" : "+v"(acc) : "v"(a), "v"(b));
    return acc;
}

__device__ __forceinline__ s16x8 ldg8(const unsigned short* p) {
    return *(const s16x8*)p;
}

typedef __attribute__((address_space(1))) const unsigned int glob_u32;
typedef __attribute__((address_space(3))) unsigned int lds_u32;
__device__ __forceinline__ void async_cp16(const void* g, void* l) {
    __builtin_amdgcn_global_load_lds((glob_u32*)g, (lds_u32*)l, 16, 0, 0);
}

__device__ __forceinline__ unsigned short f2bf(float f) {
    unsigned int u = __float_as_uint(f);
    unsigned int r = (u + 0x7FFFu + ((u >> 16) & 1u)) >> 16;
    return (unsigned short)r;
}

__device__ __forceinline__ float bf2f(unsigned short u) {
    return __uint_as_float(((unsigned int)u) << 16);
}

__device__ __forceinline__ float gelu_exact(float v) {
    return 0.5f * v * (1.0f + erff(v * 0.70710678118654752f));
}

__device__ __forceinline__ float sigmoidf_(float v) {
    return 1.0f / (1.0f + __expf(-v));
}

// ---------------- K0: fp32 -> bf16 weight conversion --------------------------
__global__ __launch_bounds__(256) void k_cvt_weights(
        const float* __restrict__ w1, const float* __restrict__ w2,
        const float* __restrict__ w3,
        unsigned short* __restrict__ o1, unsigned short* __restrict__ o2,
        unsigned short* __restrict__ o3, int n1, int n2, int n3) {
    int i = blockIdx.x * 256 + threadIdx.x;
    if (i < n1) o1[i] = f2bf(w1[i]);
    if (i < n2) o2[i] = f2bf(w2[i]);
    if (i < n3) o3[i] = f2bf(w3[i]);
}

// ---------------- K1: DualWalze (known-good) ----------------------------------
__global__ __launch_bounds__(256) void k_walze(
        const float* __restrict__ x, const float* __restrict__ dww,
        const float* __restrict__ dwb, const float* __restrict__ shw,
        const float* __restrict__ shb, const float* __restrict__ mixw,
        const float* __restrict__ gamma, const float* __restrict__ beta,
        float* __restrict__ xw) {
    __shared__ float tile[1024];
    int bc = blockIdx.x;           // b*C + c
    int c = bc & (C_ - 1);
    int tid = threadIdx.x;
    const float* xp = x + (size_t)bc * 1024;
#pragma unroll
    for (int t = 0; t < 4; ++t) tile[tid + 256 * t] = xp[tid + 256 * t];
    __syncthreads();
    float wm[9], wsh[9];
#pragma unroll
    for (int t = 0; t < 9; ++t) { wm[t] = dww[c * 9 + t]; wsh[t] = shw[t]; }
    float mix = sigmoidf_(mixw[0]);
    float bmain = dwb[c], bsh = shb[0];
    float g = gamma[c], bt = beta[c];
    const float rs = rsqrtf(1.0f + 1e-5f);
#pragma unroll
    for (int t = 0; t < 4; ++t) {
        int l = tid + 256 * t;
        int h = l >> 5, w = l & 31;
        float accm = 0.f, accs = 0.f;
#pragma unroll
        for (int kh = 0; kh < 3; ++kh) {
            int hh = (h + kh + 31) & 31;
#pragma unroll
            for (int kw = 0; kw < 3; ++kw) {
                int ww = (w + kw + 31) & 31;
                float v = tile[hh * 32 + ww];
                accm += v * wm[kh * 3 + kw];
                accs += v * wsh[kh * 3 + kw];
            }
        }
        float combined = mix * (accm + bmain) + (1.f - mix) * (accs + bsh) + tile[l];
        float bn = g * combined * rs + bt;
        xw[(size_t)bc * 1024 + l] = gelu_exact(bn);
    }
}

// ---------------- K2: LDS-tiled transpose+pack (known-good) -------------------
__global__ __launch_bounds__(256) void k_pack(
        const float* __restrict__ x, const float* __restrict__ xw,
        unsigned short* __restrict__ comb) {
    __shared__ float Tx[64 * 65];
    __shared__ float Tw[64 * 65];
    int b = blockIdx.z;
    int c0 = blockIdx.y * 64;
    int l0 = blockIdx.x * 64;
    int tid = threadIdx.x;
    for (int idx = tid; idx < 1024; idx += 256) {
        int cr = idx >> 4, f = idx & 15;
        size_t src = ((size_t)(b * C_ + c0 + cr) << 10) + l0 + f * 4;
        float4 vx = *(const float4*)(x + src);
        float4 vw = *(const float4*)(xw + src);
        *(float4*)&Tx[cr * 65 + f * 4] = vx;
        *(float4*)&Tw[cr * 65 + f * 4] = vw;
    }
    __syncthreads();
    for (int idx = tid; idx < 1024; idx += 256) {
        int lr = idx >> 4, f = idx & 15;
        ushort4 ux, uw;
        ux.x = f2bf(Tx[(4 * f + 0) * 65 + lr]);
        ux.y = f2bf(Tx[(4 * f + 1) * 65 + lr]);
        ux.z = f2bf(Tx[(4 * f + 2) * 65 + lr]);
        ux.w = f2bf(Tx[(4 * f + 3) * 65 + lr]);
        uw.x = f2bf(Tw[(4 * f + 0) * 65 + lr]);
        uw.y = f2bf(Tw[(4 * f + 1) * 65 + lr]);
        uw.z = f2bf(Tw[(4 * f + 2) * 65 + lr]);
        uw.w = f2bf(Tw[(4 * f + 3) * 65 + lr]);
        unsigned short* row = comb + (((size_t)(b << 10) + l0 + lr) << 10);
        *(ushort4*)(row + c0 + 4 * f) = ux;
        *(ushort4*)(row + 512 + c0 + 4 * f) = uw;
    }
}

// ---------------- K3: spike detector (known-good, 4-wave) ---------------------
__global__ __launch_bounds__(256) void k_detector(
        const unsigned short* __restrict__ comb, const unsigned short* __restrict__ w1,
        const float* __restrict__ b1, const float* __restrict__ w2,
        const float* __restrict__ b2, float* __restrict__ sm) {
    __shared__ float red[64];
    int tid = threadIdx.x;
    int wave = tid >> 6, lane = tid & 63;
    int col = lane & 15, quad = lane >> 4;
    int m0 = blockIdx.x * 16;
    int koff = quad * 8;
    int nb0 = wave * 32, nb1 = nb0 + 16;
    const unsigned short* pa  = comb + (size_t)(m0 + col) * 1024 + koff;
    const unsigned short* pw0 = w1 + (size_t)(nb0 + col) * 1024 + koff;
    const unsigned short* pw1 = w1 + (size_t)(nb1 + col) * 1024 + koff;
    f32x4 acc0 = {0.f, 0.f, 0.f, 0.f}, acc1 = {0.f, 0.f, 0.f, 0.f};
    for (int k = 0; k < 1024; k += 32) {
        s16x8 a = ldg8(pa + k);
        acc0 = mfma_bf16(acc0, a, ldg8(pw0 + k));
        acc1 = mfma_bf16(acc1, a, ldg8(pw1 + k));
    }
    asm volatile("s_nop 7\ns_nop 7");
    float bia0 = b1[nb0 + col], bia1 = b1[nb1 + col];
    float wv0 = w2[nb0 + col], wv1 = w2[nb1 + col];
#pragma unroll
    for (int r = 0; r < 4; ++r) {
        float h0 = gelu_exact(acc0[r] + bia0);
        float h1 = gelu_exact(acc1[r] + bia1);
        float p = h0 * wv0 + h1 * wv1;
        p += __shfl_xor(p, 1);
        p += __shfl_xor(p, 2);
        p += __shfl_xor(p, 4);
        p += __shfl_xor(p, 8);
        if (col == 0) red[wave * 16 + quad * 4 + r] = p;
    }
    __syncthreads();
    if (tid < 16) {
        float s = red[tid] + red[16 + tid] + red[32 + tid] + red[48 + tid] + b2[0];
        sm[m0 + tid] = sigmoidf_(s);
    }
}

// ---------------- K4: qkv GEMM, staged 128x128xBK64 ---------------------------
// out_hi everywhere; out_lo = bf16(v - hi) ONLY for the V region (n >= 1024):
// error ledger r3/r4/r6 shows Q/K lo buys ~0.004 absmax, V lo buys ~0.065.
__global__ __launch_bounds__(256) void k_gemm_qkv(
        const unsigned short* __restrict__ A,    // comb+512, lda=1024
        const unsigned short* __restrict__ Wt,   // [1536][512]
        const float* __restrict__ bias,
        unsigned short* __restrict__ out_hi, unsigned short* __restrict__ out_lo) {
    __shared__ unsigned short As[128 * 64];
    __shared__ unsigned short Bs[128 * 64];
    int tid = threadIdx.x;
    int wave = tid >> 6, lane = tid & 63;
    int col = lane & 15, quad = lane >> 4;
    int wr = wave & 1, wc = wave >> 1;
    int mb = blockIdx.y * 128, nb = blockIdx.x * 128;
    int srow = tid >> 3, sko = tid & 7;
    bool write_lo = (nb >= 1024);            // V region only
    f32x4 acc[4][4] = {};
    for (int kb = 0; kb < 512; kb += 64) {
#pragma unroll
        for (int p = 0; p < 4; ++p) {
            int r = p * 32 + srow;
            async_cp16(A + (size_t)(mb + r) * 1024 + kb + sko * 8, &As[r * 64 + sko * 8]);
            async_cp16(Wt + (size_t)(nb + r) * 512 + kb + sko * 8, &Bs[r * 64 + sko * 8]);
        }
        __syncthreads();
#pragma unroll
        for (int ks = 0; ks < 64; ks += 32) {
            s16x8 a[4], b[4];
#pragma unroll
            for (int i = 0; i < 4; ++i)
                a[i] = *(const s16x8*)&As[(wr * 64 + i * 16 + col) * 64 + ks + quad * 8];
#pragma unroll
            for (int j = 0; j < 4; ++j)
                b[j] = *(const s16x8*)&Bs[(wc * 64 + j * 16 + col) * 64 + ks + quad * 8];
#pragma unroll
            for (int i = 0; i < 4; ++i)
#pragma unroll
                for (int j = 0; j < 4; ++j)
                    acc[i][j] = mfma_bf16(acc[i][j], a[i], b[j]);
        }
        __syncthreads();
    }
    asm volatile("s_nop 7\ns_nop 7");
#pragma unroll
    for (int i = 0; i < 4; ++i)
#pragma unroll
        for (int j = 0; j < 4; ++j) {
            int n = nb + wc * 64 + j * 16 + col;
            float bv = bias[n];
#pragma unroll
            for (int r = 0; r < 4; ++r) {
                int m = mb + wr * 64 + i * 16 + quad * 4 + r;
                float v = acc[i][j][r] + bv;
                unsigned short hi = f2bf(v);
                size_t idx = (size_t)m * 1536 + n;
                out_hi[idx] = hi;
                if (write_lo) out_lo[idx] = f2bf(v - bf2f(hi));
            }
        }
}

// ---------------- K5: windowed attention via MFMA -----------------------------
// Q,K bf16-hi only (S = 2 MFMAs per live tile); windowed S (<=3 live tiles);
// P NORMALIZED, split hi/lo; V hi+lo; PV: O = Ph.Vh + Pl.Vh + Ph.Vl.
__global__ __launch_bounds__(256) void k_attn(
        const unsigned short* __restrict__ qkv_hi,
        const unsigned short* __restrict__ qkv_lo,
        unsigned short* __restrict__ ctx) {
    __shared__ unsigned short Vth[64 * 112];      // V hi [d][key], ld=112 (96 real + 16 zero pad)
    __shared__ unsigned short Vtl[64 * 112];      // V lo
    __shared__ unsigned short Ph[4][16 * 72];     // per-wave P hi [m][window-key], ld=72
    __shared__ unsigned short Pl[4][16 * 72];     // per-wave P lo
    int b = blockIdx.z, h = blockIdx.y;
    int q0 = blockIdx.x * 64;
    int tid = threadIdx.x, wave = tid >> 6, lane = tid & 63;
    int col = lane & 15, quad = lane >> 4;
    int jlo_t = max(q0 - 16, 0);
    const unsigned short* baseh = qkv_hi + ((size_t)(b << 10)) * 1536;
    const unsigned short* basel = qkv_lo + ((size_t)(b << 10)) * 1536;
    // stage V^T hi and lo: 12 key-groups x 64 d
#pragma unroll
    for (int it = 0; it < 3; ++it) {
        int slot = it * 256 + tid;
        int kg = slot >> 6, d = slot & 63;
        int key0 = jlo_t + kg * 8;
        unsigned short eh[8], el[8];
#pragma unroll
        for (int t = 0; t < 8; ++t) {
            size_t ro = (size_t)min(key0 + t, 1023) * 1536 + 1024 + h * 64 + d;
            eh[t] = baseh[ro];
            el[t] = basel[ro];
        }
        ushort4 h0 = {eh[0], eh[1], eh[2], eh[3]}, h1 = {eh[4], eh[5], eh[6], eh[7]};
        ushort4 l0 = {el[0], el[1], el[2], el[3]}, l1 = {el[4], el[5], el[6], el[7]};
        *(ushort4*)&Vth[d * 112 + kg * 8] = h0;
        *(ushort4*)&Vth[d * 112 + kg * 8 + 4] = h1;
        *(ushort4*)&Vtl[d * 112 + kg * 8] = l0;
        *(ushort4*)&Vtl[d * 112 + kg * 8 + 4] = l1;
    }
    // zero V pad keys [96,112)
    {
        int d = tid >> 2, c4 = (tid & 3) * 4;
        ushort4 z = {0, 0, 0, 0};
        *(ushort4*)&Vth[d * 112 + 96 + c4] = z;
        *(ushort4*)&Vtl[d * 112 + 96 + c4] = z;
    }
    __syncthreads();
    // Q A-frags (hi only)
    int i_min = q0 + wave * 16;
    size_t qoff = (size_t)(i_min + col) * 1536 + h * 64;
    s16x8 aq0h = ldg8(baseh + qoff + quad * 8);
    s16x8 aq1h = ldg8(baseh + qoff + 32 + quad * 8);
    // live key-tile range for this wave (wave-uniform, <=3 tiles)
    int t0 = (max(i_min - 16, 0) - jlo_t) >> 4;
    int t1 = (min(i_min + 31, 1023) - jlo_t) >> 4;
    // S over live tiles only, hi-only operands
    f32x4 S[3];
#pragma unroll
    for (int u = 0; u < 3; ++u) {
        int nt = t0 + u;
        size_t koffb = (size_t)min(jlo_t + nt * 16 + col, 1023) * 1536 + 512 + h * 64;
        s16x8 kh0 = ldg8(baseh + koffb + quad * 8);
        s16x8 kh1 = ldg8(baseh + koffb + 32 + quad * 8);
        f32x4 z = {0.f, 0.f, 0.f, 0.f};
        z = mfma_bf16(z, aq0h, kh0);
        z = mfma_bf16(z, aq1h, kh1);
        S[u] = z;
    }
    asm volatile("s_nop 7\ns_nop 7");
    // masked softmax per row r
    int i_base = i_min + quad * 4;
    float mx[4] = {-1e30f, -1e30f, -1e30f, -1e30f};
#pragma unroll
    for (int u = 0; u < 3; ++u) {
        int nt = t0 + u;
        int j = jlo_t + nt * 16 + col;
        bool live = (nt <= t1);
#pragma unroll
        for (int r = 0; r < 4; ++r) {
            int i = i_base + r;
            bool ok = live && (j <= 1023) && (j >= i - 16) && (j <= i + 16);
            float s = ok ? S[u][r] * 0.125f : -1e30f;
            S[u][r] = s;
            mx[r] = fmaxf(mx[r], s);
        }
    }
#pragma unroll
    for (int r = 0; r < 4; ++r) {
        mx[r] = fmaxf(mx[r], __shfl_xor(mx[r], 1));
        mx[r] = fmaxf(mx[r], __shfl_xor(mx[r], 2));
        mx[r] = fmaxf(mx[r], __shfl_xor(mx[r], 4));
        mx[r] = fmaxf(mx[r], __shfl_xor(mx[r], 8));
    }
    float sum[4] = {0.f, 0.f, 0.f, 0.f};
#pragma unroll
    for (int u = 0; u < 3; ++u)
#pragma unroll
        for (int r = 0; r < 4; ++r) {
            float p = __expf(S[u][r] - mx[r]);   // masked -> 0
            S[u][r] = p;
            sum[r] += p;
        }
#pragma unroll
    for (int r = 0; r < 4; ++r) {
        sum[r] += __shfl_xor(sum[r], 1);
        sum[r] += __shfl_xor(sum[r], 2);
        sum[r] += __shfl_xor(sum[r], 4);
        sum[r] += __shfl_xor(sum[r], 8);
        sum[r] = 1.f / sum[r];
    }
    int wbase = t0 * 16;                     // window base within staged keys
    // zero P pad cols [48,64)
    {
        int pr = lane >> 2, c4 = (lane & 3) * 4;
        ushort4 z = {0, 0, 0, 0};
        *(ushort4*)&Ph[wave][pr * 72 + 48 + c4] = z;
        *(ushort4*)&Pl[wave][pr * 72 + 48 + c4] = z;
    }
    // NORMALIZED P -> windowed LDS, split hi/lo (pcol = u*16+col covers [0,48))
#pragma unroll
    for (int u = 0; u < 3; ++u) {
        int pcol = u * 16 + col;
#pragma unroll
        for (int r = 0; r < 4; ++r) {
            float pv = S[u][r] * sum[r];     // 0 for dead tiles
            unsigned short hi = f2bf(pv);
            Ph[wave][(quad * 4 + r) * 72 + pcol] = hi;
            Pl[wave][(quad * 4 + r) * 72 + pcol] = f2bf(pv - bf2f(hi));
        }
    }
    __syncthreads();
    // O = Ph.Vh + Pl.Vh + Ph.Vl over the 64-key window
    f32x4 O[4] = {};
#pragma unroll
    for (int ks = 0; ks < 64; ks += 32) {
        s16x8 aph = *(const s16x8*)&Ph[wave][col * 72 + ks + quad * 8];
        s16x8 apl = *(const s16x8*)&Pl[wave][col * 72 + ks + quad * 8];
#pragma unroll
        for (int nt = 0; nt < 4; ++nt) {
            s16x8 bvh = *(const s16x8*)&Vth[(nt * 16 + col) * 112 + wbase + ks + quad * 8];
            s16x8 bvl = *(const s16x8*)&Vtl[(nt * 16 + col) * 112 + wbase + ks + quad * 8];
            O[nt] = mfma_bf16(O[nt], aph, bvh);
            O[nt] = mfma_bf16(O[nt], apl, bvh);
            O[nt] = mfma_bf16(O[nt], aph, bvl);
        }
    }
    asm volatile("s_nop 7\ns_nop 7");
#pragma unroll
    for (int nt = 0; nt < 4; ++nt)
#pragma unroll
        for (int r = 0; r < 4; ++r) {
            int i = i_base + r;
            ctx[((size_t)(b << 10) + i) * 512 + h * 64 + nt * 16 + col] = f2bf(O[nt][r]);
        }
}

// ---------------- K6: out-proj GEMM + gated combine, 64x64 tiles --------------
__global__ __launch_bounds__(256) void k_out_combine(
        const unsigned short* __restrict__ Wt, const unsigned short* __restrict__ Actx,
        const float* __restrict__ bias, const float* __restrict__ xw,
        const float* __restrict__ sm, float* __restrict__ out) {
    __shared__ unsigned short As[64 * 64];
    __shared__ unsigned short Bs[64 * 64];
    int tid = threadIdx.x;
    int wave = tid >> 6, lane = tid & 63;
    int col = lane & 15, quad = lane >> 4;
    int wr = wave & 1, wc = wave >> 1;
    int mb = blockIdx.y * 64, nb = blockIdx.x * 64;
    int srow = tid >> 3, sko = tid & 7;
    f32x4 acc[2][2] = {};
    for (int kb = 0; kb < 512; kb += 64) {
#pragma unroll
        for (int p = 0; p < 2; ++p) {
            int r = p * 32 + srow;
            async_cp16(Wt + (size_t)(mb + r) * 512 + kb + sko * 8, &As[r * 64 + sko * 8]);
            async_cp16(Actx + (size_t)(nb + r) * 512 + kb + sko * 8, &Bs[r * 64 + sko * 8]);
        }
        __syncthreads();
#pragma unroll
        for (int ks = 0; ks < 64; ks += 32) {
            s16x8 a[2], b[2];
#pragma unroll
            for (int i = 0; i < 2; ++i)
                a[i] = *(const s16x8*)&As[(wr * 32 + i * 16 + col) * 64 + ks + quad * 8];
#pragma unroll
            for (int j = 0; j < 2; ++j)
                b[j] = *(const s16x8*)&Bs[(wc * 32 + j * 16 + col) * 64 + ks + quad * 8];
#pragma unroll
            for (int i = 0; i < 2; ++i)
#pragma unroll
                for (int j = 0; j < 2; ++j)
                    acc[i][j] = mfma_bf16(acc[i][j], a[i], b[j]);
        }
        __syncthreads();
    }
    asm volatile("s_nop 7\ns_nop 7");
#pragma unroll
    for (int i = 0; i < 2; ++i)
#pragma unroll
        for (int j = 0; j < 2; ++j) {
            int seq = nb + wc * 32 + j * 16 + col;
            int bb = seq >> 10, l = seq & 1023;
            float smv = sm[seq];
#pragma unroll
            for (int r = 0; r < 4; ++r) {
                int c = mb + wr * 32 + i * 16 + quad * 4 + r;
                float v = acc[i][j][r] + bias[c];
                size_t oidx = ((size_t)(bb * C_ + c) << 10) + l;
                out[oidx] = xw[oidx] + smv * v;
            }
        }
}

extern "C" void kernel_launch(void* const* d_in, const int* in_sizes, int n_in,
                              void* d_out, int out_size, void* d_ws, size_t ws_size,
                              hipStream_t stream) {
    const float* x      = (const float*)d_in[0];
    const float* dw_w   = (const float*)d_in[1];
    const float* dw_b   = (const float*)d_in[2];
    const float* sh_w   = (const float*)d_in[3];
    const float* sh_b   = (const float*)d_in[4];
    const float* mix_w  = (const float*)d_in[5];
    const float* bn_g   = (const float*)d_in[6];
    const float* bn_b   = (const float*)d_in[7];
    const float* det_w1 = (const float*)d_in[8];
    const float* det_b1 = (const float*)d_in[9];
    const float* det_w2 = (const float*)d_in[10];
    const float* det_b2 = (const float*)d_in[11];
    const float* inp_w  = (const float*)d_in[12];
    const float* inp_b  = (const float*)d_in[13];
    const float* outp_w = (const float*)d_in[14];
    const float* outp_b = (const float*)d_in[15];
    float* out = (float*)d_out;

    char* ws = (char*)d_ws;
    size_t off = 0;
    auto alloc = [&](size_t bytes) -> void* {
        void* p = ws + off;
        off += (bytes + 255) & ~(size_t)255;
        return p;
    };
    float* xw             = (float*)alloc((size_t)M_ * C_ * 4);
    unsigned short* comb  = (unsigned short*)alloc((size_t)M_ * 1024 * 2);
    unsigned short* qkvh  = (unsigned short*)alloc((size_t)M_ * 1536 * 2);
    unsigned short* qkvl  = (unsigned short*)alloc((size_t)M_ * 1536 * 2);
    unsigned short* ctx   = (unsigned short*)alloc((size_t)M_ * 512 * 2);
    float* smask          = (float*)alloc((size_t)M_ * 4);
    unsigned short* w1b   = (unsigned short*)alloc(131072 * 2);
    unsigned short* inwb  = (unsigned short*)alloc(786432 * 2);
    unsigned short* outwb = (unsigned short*)alloc(262144 * 2);
    (void)ws_size; (void)in_sizes; (void)n_in; (void)out_size;

    k_cvt_weights<<<3072, 256, 0, stream>>>(det_w1, inp_w, outp_w, w1b, inwb, outwb,
                                            131072, 786432, 262144);
    k_walze<<<B_ * C_, 256, 0, stream>>>(x, dw_w, dw_b, sh_w, sh_b, mix_w, bn_g, bn_b, xw);
    k_pack<<<dim3(16, 8, 8), 256, 0, stream>>>(x, xw, comb);
    k_detector<<<M_ / 16, 256, 0, stream>>>(comb, w1b, det_b1, det_w2, det_b2, smask);
    k_gemm_qkv<<<dim3(1536 / 128, M_ / 128), 256, 0, stream>>>(comb + 512, inwb, inp_b,
                                                               qkvh, qkvl);
    k_attn<<<dim3(16, NH_, B_), 256, 0, stream>>>(qkvh, qkvl, ctx);
    k_out_combine<<<dim3(M_ / 64, C_ / 64), 256, 0, stream>>>(outwb, ctx, outp_b,
                                                              xw, smask, out);
}

// Round 12
// 180.818 us; speedup vs baseline: 1.1204x; 1.0353x over previous
//
#include <hip/hip_runtime.h>

#define B_ 8
#define C_ 512
#define H_ 32
#define W_ 32
#define L_ 1024
#define M_ 8192   // B*L
#define NH_ 8
#define HD_ 64

typedef float f32x4 __attribute__((ext_vector_type(4)));
typedef short s16x8 __attribute__((ext_vector_type(8)));

// MFMA 16x16x32 bf16. C/D: col=lane&15 (n), row=(lane>>4)*4+reg (m).
// A frag: row m=lane&15, k=(lane>>4)*8+j ; B frag from B^T [n][k]: row n=lane&15.
__device__ __forceinline__ f32x4 mfma_bf16(f32x4 acc, s16x8 a, s16x8 b) {
    asm("v_mfma_f32_16x16x32_bf16 %0, %1, %2, %0" : "+v"(acc) : "v"(a), "v"(b));
    return acc;
}

__device__ __forceinline__ s16x8 ldg8(const unsigned short* p) {
    return *(const s16x8*)p;
}

typedef __attribute__((address_space(1))) const unsigned int glob_u32;
typedef __attribute__((address_space(3))) unsigned int lds_u32;
__device__ __forceinline__ void async_cp16(const void* g, void* l) {
    __builtin_amdgcn_global_load_lds((glob_u32*)g, (lds_u32*)l, 16, 0, 0);
}

__device__ __forceinline__ unsigned short f2bf(float f) {
    unsigned int u = __float_as_uint(f);
    unsigned int r = (u + 0x7FFFu + ((u >> 16) & 1u)) >> 16;
    return (unsigned short)r;
}

__device__ __forceinline__ float bf2f(unsigned short u) {
    return __uint_as_float(((unsigned int)u) << 16);
}

__device__ __forceinline__ float gelu_exact(float v) {
    return 0.5f * v * (1.0f + erff(v * 0.70710678118654752f));
}

__device__ __forceinline__ float sigmoidf_(float v) {
    return 1.0f / (1.0f + __expf(-v));
}

// ---------------- K1: DualWalze + fused fp32->bf16 weight conversion ----------
// Weight cvt folded in: 4096 blocks x 256 threads cover 1,179,648 weight elems
// in <=2 strided slots/thread; hidden behind the LDS conv work.
__global__ __launch_bounds__(256) void k_walze_cvt(
        const float* __restrict__ x, const float* __restrict__ dww,
        const float* __restrict__ dwb, const float* __restrict__ shw,
        const float* __restrict__ shb, const float* __restrict__ mixw,
        const float* __restrict__ gamma, const float* __restrict__ beta,
        float* __restrict__ xw,
        const float* __restrict__ w1, const float* __restrict__ w2,
        const float* __restrict__ w3,
        unsigned short* __restrict__ o1, unsigned short* __restrict__ o2,
        unsigned short* __restrict__ o3) {
    __shared__ float tile[1024];
    int bc = blockIdx.x;           // b*C + c
    int c = bc & (C_ - 1);
    int tid = threadIdx.x;
    const float* xp = x + (size_t)bc * 1024;
#pragma unroll
    for (int t = 0; t < 4; ++t) tile[tid + 256 * t] = xp[tid + 256 * t];
    // weight conversion while the tile loads settle (n1=131072, n2=786432, n3=262144)
    {
        int g = bc * 256 + tid;
#pragma unroll
        for (int t = 0; t < 2; ++t) {
            int i = g + t * 1048576;
            if (i < 131072) o1[i] = f2bf(w1[i]);
            else if (i < 917504) o2[i - 131072] = f2bf(w2[i - 131072]);
            else if (i < 1179648) o3[i - 917504] = f2bf(w3[i - 917504]);
        }
    }
    __syncthreads();
    float wm[9], wsh[9];
#pragma unroll
    for (int t = 0; t < 9; ++t) { wm[t] = dww[c * 9 + t]; wsh[t] = shw[t]; }
    float mix = sigmoidf_(mixw[0]);
    float bmain = dwb[c], bsh = shb[0];
    float g = gamma[c], bt = beta[c];
    const float rs = rsqrtf(1.0f + 1e-5f);
#pragma unroll
    for (int t = 0; t < 4; ++t) {
        int l = tid + 256 * t;
        int h = l >> 5, w = l & 31;
        float accm = 0.f, accs = 0.f;
#pragma unroll
        for (int kh = 0; kh < 3; ++kh) {
            int hh = (h + kh + 31) & 31;
#pragma unroll
            for (int kw = 0; kw < 3; ++kw) {
                int ww = (w + kw + 31) & 31;
                float v = tile[hh * 32 + ww];
                accm += v * wm[kh * 3 + kw];
                accs += v * wsh[kh * 3 + kw];
            }
        }
        float combined = mix * (accm + bmain) + (1.f - mix) * (accs + bsh) + tile[l];
        float bn = g * combined * rs + bt;
        xw[(size_t)bc * 1024 + l] = gelu_exact(bn);
    }
}

// ---------------- K2: LDS-tiled transpose+pack (known-good) -------------------
__global__ __launch_bounds__(256) void k_pack(
        const float* __restrict__ x, const float* __restrict__ xw,
        unsigned short* __restrict__ comb) {
    __shared__ float Tx[64 * 65];
    __shared__ float Tw[64 * 65];
    int b = blockIdx.z;
    int c0 = blockIdx.y * 64;
    int l0 = blockIdx.x * 64;
    int tid = threadIdx.x;
    for (int idx = tid; idx < 1024; idx += 256) {
        int cr = idx >> 4, f = idx & 15;
        size_t src = ((size_t)(b * C_ + c0 + cr) << 10) + l0 + f * 4;
        float4 vx = *(const float4*)(x + src);
        float4 vw = *(const float4*)(xw + src);
        *(float4*)&Tx[cr * 65 + f * 4] = vx;
        *(float4*)&Tw[cr * 65 + f * 4] = vw;
    }
    __syncthreads();
    for (int idx = tid; idx < 1024; idx += 256) {
        int lr = idx >> 4, f = idx & 15;
        ushort4 ux, uw;
        ux.x = f2bf(Tx[(4 * f + 0) * 65 + lr]);
        ux.y = f2bf(Tx[(4 * f + 1) * 65 + lr]);
        ux.z = f2bf(Tx[(4 * f + 2) * 65 + lr]);
        ux.w = f2bf(Tx[(4 * f + 3) * 65 + lr]);
        uw.x = f2bf(Tw[(4 * f + 0) * 65 + lr]);
        uw.y = f2bf(Tw[(4 * f + 1) * 65 + lr]);
        uw.z = f2bf(Tw[(4 * f + 2) * 65 + lr]);
        uw.w = f2bf(Tw[(4 * f + 3) * 65 + lr]);
        unsigned short* row = comb + (((size_t)(b << 10) + l0 + lr) << 10);
        *(ushort4*)(row + c0 + 4 * f) = ux;
        *(ushort4*)(row + 512 + c0 + 4 * f) = uw;
    }
}

// ---------------- K3+K4 fused: block-specialized detector | qkv GEMM ----------
// Blocks [0,512): spike detector (latency-bound, VALU). Blocks [512,1280):
// qkv GEMM 128x128 (MFMA-bound). Independent work, same inputs (comb);
// co-resident waves overlap MFMA and VALU/latency pipes (m114).
__global__ __launch_bounds__(256) void k_det_qkv(
        const unsigned short* __restrict__ comb,
        const unsigned short* __restrict__ w1, const float* __restrict__ b1,
        const float* __restrict__ w2, const float* __restrict__ b2,
        float* __restrict__ sm,
        const unsigned short* __restrict__ Wt, const float* __restrict__ bias,
        unsigned short* __restrict__ out_hi, unsigned short* __restrict__ out_lo) {
    __shared__ unsigned short As[128 * 64];
    __shared__ unsigned short Bs[128 * 64];
    int tid = threadIdx.x;
    int wave = tid >> 6, lane = tid & 63;
    int col = lane & 15, quad = lane >> 4;
    if (blockIdx.x < 512) {
        // ---- detector body (round-6 known-good) ----
        float* red = (float*)As;              // 256 B of the union
        int m0 = blockIdx.x * 16;
        int koff = quad * 8;
        int nb0 = wave * 32, nb1 = nb0 + 16;
        const unsigned short* pa  = comb + (size_t)(m0 + col) * 1024 + koff;
        const unsigned short* pw0 = w1 + (size_t)(nb0 + col) * 1024 + koff;
        const unsigned short* pw1 = w1 + (size_t)(nb1 + col) * 1024 + koff;
        f32x4 acc0 = {0.f, 0.f, 0.f, 0.f}, acc1 = {0.f, 0.f, 0.f, 0.f};
        for (int k = 0; k < 1024; k += 32) {
            s16x8 a = ldg8(pa + k);
            acc0 = mfma_bf16(acc0, a, ldg8(pw0 + k));
            acc1 = mfma_bf16(acc1, a, ldg8(pw1 + k));
        }
        asm volatile("s_nop 7\ns_nop 7");
        float bia0 = b1[nb0 + col], bia1 = b1[nb1 + col];
        float wv0 = w2[nb0 + col], wv1 = w2[nb1 + col];
#pragma unroll
        for (int r = 0; r < 4; ++r) {
            float h0 = gelu_exact(acc0[r] + bia0);
            float h1 = gelu_exact(acc1[r] + bia1);
            float p = h0 * wv0 + h1 * wv1;
            p += __shfl_xor(p, 1);
            p += __shfl_xor(p, 2);
            p += __shfl_xor(p, 4);
            p += __shfl_xor(p, 8);
            if (col == 0) red[wave * 16 + quad * 4 + r] = p;
        }
        __syncthreads();
        if (tid < 16) {
            float s = red[tid] + red[16 + tid] + red[32 + tid] + red[48 + tid] + b2[0];
            sm[m0 + tid] = sigmoidf_(s);
        }
    } else {
        // ---- qkv GEMM body (round-11 known-good), flattened grid ----
        int qbid = blockIdx.x - 512;          // 0..767
        int nb = (qbid % 12) * 128;
        int mb = (qbid / 12) * 128;
        const unsigned short* A = comb + 512; // xw half, lda=1024
        int wr = wave & 1, wc = wave >> 1;
        int srow = tid >> 3, sko = tid & 7;
        bool write_lo = (nb >= 1024);         // V region only
        f32x4 acc[4][4] = {};
        for (int kb = 0; kb < 512; kb += 64) {
#pragma unroll
            for (int p = 0; p < 4; ++p) {
                int r = p * 32 + srow;
                async_cp16(A + (size_t)(mb + r) * 1024 + kb + sko * 8, &As[r * 64 + sko * 8]);
                async_cp16(Wt + (size_t)(nb + r) * 512 + kb + sko * 8, &Bs[r * 64 + sko * 8]);
            }
            __syncthreads();
#pragma unroll
            for (int ks = 0; ks < 64; ks += 32) {
                s16x8 a[4], b[4];
#pragma unroll
                for (int i = 0; i < 4; ++i)
                    a[i] = *(const s16x8*)&As[(wr * 64 + i * 16 + col) * 64 + ks + quad * 8];
#pragma unroll
                for (int j = 0; j < 4; ++j)
                    b[j] = *(const s16x8*)&Bs[(wc * 64 + j * 16 + col) * 64 + ks + quad * 8];
#pragma unroll
                for (int i = 0; i < 4; ++i)
#pragma unroll
                    for (int j = 0; j < 4; ++j)
                        acc[i][j] = mfma_bf16(acc[i][j], a[i], b[j]);
            }
            __syncthreads();
        }
        asm volatile("s_nop 7\ns_nop 7");
#pragma unroll
        for (int i = 0; i < 4; ++i)
#pragma unroll
            for (int j = 0; j < 4; ++j) {
                int n = nb + wc * 64 + j * 16 + col;
                float bv = bias[n];
#pragma unroll
                for (int r = 0; r < 4; ++r) {
                    int m = mb + wr * 64 + i * 16 + quad * 4 + r;
                    float v = acc[i][j][r] + bv;
                    unsigned short hi = f2bf(v);
                    size_t idx = (size_t)m * 1536 + n;
                    out_hi[idx] = hi;
                    if (write_lo) out_lo[idx] = f2bf(v - bf2f(hi));
                }
            }
    }
}

// ---------------- K5: windowed attention via MFMA (round-11 known-good) -------
__global__ __launch_bounds__(256) void k_attn(
        const unsigned short* __restrict__ qkv_hi,
        const unsigned short* __restrict__ qkv_lo,
        unsigned short* __restrict__ ctx) {
    __shared__ unsigned short Vth[64 * 112];      // V hi [d][key], ld=112 (96 real + 16 zero pad)
    __shared__ unsigned short Vtl[64 * 112];      // V lo
    __shared__ unsigned short Ph[4][16 * 72];     // per-wave P hi [m][window-key], ld=72
    __shared__ unsigned short Pl[4][16 * 72];     // per-wave P lo
    int b = blockIdx.z, h = blockIdx.y;
    int q0 = blockIdx.x * 64;
    int tid = threadIdx.x, wave = tid >> 6, lane = tid & 63;
    int col = lane & 15, quad = lane >> 4;
    int jlo_t = max(q0 - 16, 0);
    const unsigned short* baseh = qkv_hi + ((size_t)(b << 10)) * 1536;
    const unsigned short* basel = qkv_lo + ((size_t)(b << 10)) * 1536;
#pragma unroll
    for (int it = 0; it < 3; ++it) {
        int slot = it * 256 + tid;
        int kg = slot >> 6, d = slot & 63;
        int key0 = jlo_t + kg * 8;
        unsigned short eh[8], el[8];
#pragma unroll
        for (int t = 0; t < 8; ++t) {
            size_t ro = (size_t)min(key0 + t, 1023) * 1536 + 1024 + h * 64 + d;
            eh[t] = baseh[ro];
            el[t] = basel[ro];
        }
        ushort4 h0 = {eh[0], eh[1], eh[2], eh[3]}, h1 = {eh[4], eh[5], eh[6], eh[7]};
        ushort4 l0 = {el[0], el[1], el[2], el[3]}, l1 = {el[4], el[5], el[6], el[7]};
        *(ushort4*)&Vth[d * 112 + kg * 8] = h0;
        *(ushort4*)&Vth[d * 112 + kg * 8 + 4] = h1;
        *(ushort4*)&Vtl[d * 112 + kg * 8] = l0;
        *(ushort4*)&Vtl[d * 112 + kg * 8 + 4] = l1;
    }
    // zero V pad keys [96,112)
    {
        int d = tid >> 2, c4 = (tid & 3) * 4;
        ushort4 z = {0, 0, 0, 0};
        *(ushort4*)&Vth[d * 112 + 96 + c4] = z;
        *(ushort4*)&Vtl[d * 112 + 96 + c4] = z;
    }
    __syncthreads();
    // Q A-frags (hi only)
    int i_min = q0 + wave * 16;
    size_t qoff = (size_t)(i_min + col) * 1536 + h * 64;
    s16x8 aq0h = ldg8(baseh + qoff + quad * 8);
    s16x8 aq1h = ldg8(baseh + qoff + 32 + quad * 8);
    // live key-tile range for this wave (wave-uniform, <=3 tiles)
    int t0 = (max(i_min - 16, 0) - jlo_t) >> 4;
    int t1 = (min(i_min + 31, 1023) - jlo_t) >> 4;
    f32x4 S[3];
#pragma unroll
    for (int u = 0; u < 3; ++u) {
        int nt = t0 + u;
        size_t koffb = (size_t)min(jlo_t + nt * 16 + col, 1023) * 1536 + 512 + h * 64;
        s16x8 kh0 = ldg8(baseh + koffb + quad * 8);
        s16x8 kh1 = ldg8(baseh + koffb + 32 + quad * 8);
        f32x4 z = {0.f, 0.f, 0.f, 0.f};
        z = mfma_bf16(z, aq0h, kh0);
        z = mfma_bf16(z, aq1h, kh1);
        S[u] = z;
    }
    asm volatile("s_nop 7\ns_nop 7");
    int i_base = i_min + quad * 4;
    float mx[4] = {-1e30f, -1e30f, -1e30f, -1e30f};
#pragma unroll
    for (int u = 0; u < 3; ++u) {
        int nt = t0 + u;
        int j = jlo_t + nt * 16 + col;
        bool live = (nt <= t1);
#pragma unroll
        for (int r = 0; r < 4; ++r) {
            int i = i_base + r;
            bool ok = live && (j <= 1023) && (j >= i - 16) && (j <= i + 16);
            float s = ok ? S[u][r] * 0.125f : -1e30f;
            S[u][r] = s;
            mx[r] = fmaxf(mx[r], s);
        }
    }
#pragma unroll
    for (int r = 0; r < 4; ++r) {
        mx[r] = fmaxf(mx[r], __shfl_xor(mx[r], 1));
        mx[r] = fmaxf(mx[r], __shfl_xor(mx[r], 2));
        mx[r] = fmaxf(mx[r], __shfl_xor(mx[r], 4));
        mx[r] = fmaxf(mx[r], __shfl_xor(mx[r], 8));
    }
    float sum[4] = {0.f, 0.f, 0.f, 0.f};
#pragma unroll
    for (int u = 0; u < 3; ++u)
#pragma unroll
        for (int r = 0; r < 4; ++r) {
            float p = __expf(S[u][r] - mx[r]);
            S[u][r] = p;
            sum[r] += p;
        }
#pragma unroll
    for (int r = 0; r < 4; ++r) {
        sum[r] += __shfl_xor(sum[r], 1);
        sum[r] += __shfl_xor(sum[r], 2);
        sum[r] += __shfl_xor(sum[r], 4);
        sum[r] += __shfl_xor(sum[r], 8);
        sum[r] = 1.f / sum[r];
    }
    int wbase = t0 * 16;
    // zero P pad cols [48,64)
    {
        int pr = lane >> 2, c4 = (lane & 3) * 4;
        ushort4 z = {0, 0, 0, 0};
        *(ushort4*)&Ph[wave][pr * 72 + 48 + c4] = z;
        *(ushort4*)&Pl[wave][pr * 72 + 48 + c4] = z;
    }
#pragma unroll
    for (int u = 0; u < 3; ++u) {
        int pcol = u * 16 + col;
#pragma unroll
        for (int r = 0; r < 4; ++r) {
            float pv = S[u][r] * sum[r];
            unsigned short hi = f2bf(pv);
            Ph[wave][(quad * 4 + r) * 72 + pcol] = hi;
            Pl[wave][(quad * 4 + r) * 72 + pcol] = f2bf(pv - bf2f(hi));
        }
    }
    __syncthreads();
    f32x4 O[4] = {};
#pragma unroll
    for (int ks = 0; ks < 64; ks += 32) {
        s16x8 aph = *(const s16x8*)&Ph[wave][col * 72 + ks + quad * 8];
        s16x8 apl = *(const s16x8*)&Pl[wave][col * 72 + ks + quad * 8];
#pragma unroll
        for (int nt = 0; nt < 4; ++nt) {
            s16x8 bvh = *(const s16x8*)&Vth[(nt * 16 + col) * 112 + wbase + ks + quad * 8];
            s16x8 bvl = *(const s16x8*)&Vtl[(nt * 16 + col) * 112 + wbase + ks + quad * 8];
            O[nt] = mfma_bf16(O[nt], aph, bvh);
            O[nt] = mfma_bf16(O[nt], apl, bvh);
            O[nt] = mfma_bf16(O[nt], aph, bvl);
        }
    }
    asm volatile("s_nop 7\ns_nop 7");
#pragma unroll
    for (int nt = 0; nt < 4; ++nt)
#pragma unroll
        for (int r = 0; r < 4; ++r) {
            int i = i_base + r;
            ctx[((size_t)(b << 10) + i) * 512 + h * 64 + nt * 16 + col] = f2bf(O[nt][r]);
        }
}

// ---------------- K6: out-proj GEMM + gated combine, 64x64 tiles --------------
__global__ __launch_bounds__(256) void k_out_combine(
        const unsigned short* __restrict__ Wt, const unsigned short* __restrict__ Actx,
        const float* __restrict__ bias, const float* __restrict__ xw,
        const float* __restrict__ sm, float* __restrict__ out) {
    __shared__ unsigned short As[64 * 64];
    __shared__ unsigned short Bs[64 * 64];
    int tid = threadIdx.x;
    int wave = tid >> 6, lane = tid & 63;
    int col = lane & 15, quad = lane >> 4;
    int wr = wave & 1, wc = wave >> 1;
    int mb = blockIdx.y * 64, nb = blockIdx.x * 64;
    int srow = tid >> 3, sko = tid & 7;
    f32x4 acc[2][2] = {};
    for (int kb = 0; kb < 512; kb += 64) {
#pragma unroll
        for (int p = 0; p < 2; ++p) {
            int r = p * 32 + srow;
            async_cp16(Wt + (size_t)(mb + r) * 512 + kb + sko * 8, &As[r * 64 + sko * 8]);
            async_cp16(Actx + (size_t)(nb + r) * 512 + kb + sko * 8, &Bs[r * 64 + sko * 8]);
        }
        __syncthreads();
#pragma unroll
        for (int ks = 0; ks < 64; ks += 32) {
            s16x8 a[2], b[2];
#pragma unroll
            for (int i = 0; i < 2; ++i)
                a[i] = *(const s16x8*)&As[(wr * 32 + i * 16 + col) * 64 + ks + quad * 8];
#pragma unroll
            for (int j = 0; j < 2; ++j)
                b[j] = *(const s16x8*)&Bs[(wc * 32 + j * 16 + col) * 64 + ks + quad * 8];
#pragma unroll
            for (int i = 0; i < 2; ++i)
#pragma unroll
                for (int j = 0; j < 2; ++j)
                    acc[i][j] = mfma_bf16(acc[i][j], a[i], b[j]);
        }
        __syncthreads();
    }
    asm volatile("s_nop 7\ns_nop 7");
#pragma unroll
    for (int i = 0; i < 2; ++i)
#pragma unroll
        for (int j = 0; j < 2; ++j) {
            int seq = nb + wc * 32 + j * 16 + col;
            int bb = seq >> 10, l = seq & 1023;
            float smv = sm[seq];
#pragma unroll
            for (int r = 0; r < 4; ++r) {
                int c = mb + wr * 32 + i * 16 + quad * 4 + r;
                float v = acc[i][j][r] + bias[c];
                size_t oidx = ((size_t)(bb * C_ + c) << 10) + l;
                out[oidx] = xw[oidx] + smv * v;
            }
        }
}

extern "C" void kernel_launch(void* const* d_in, const int* in_sizes, int n_in,
                              void* d_out, int out_size, void* d_ws, size_t ws_size,
                              hipStream_t stream) {
    const float* x      = (const float*)d_in[0];
    const float* dw_w   = (const float*)d_in[1];
    const float* dw_b   = (const float*)d_in[2];
    const float* sh_w   = (const float*)d_in[3];
    const float* sh_b   = (const float*)d_in[4];
    const float* mix_w  = (const float*)d_in[5];
    const float* bn_g   = (const float*)d_in[6];
    const float* bn_b   = (const float*)d_in[7];
    const float* det_w1 = (const float*)d_in[8];
    const float* det_b1 = (const float*)d_in[9];
    const float* det_w2 = (const float*)d_in[10];
    const float* det_b2 = (const float*)d_in[11];
    const float* inp_w  = (const float*)d_in[12];
    const float* inp_b  = (const float*)d_in[13];
    const float* outp_w = (const float*)d_in[14];
    const float* outp_b = (const float*)d_in[15];
    float* out = (float*)d_out;

    char* ws = (char*)d_ws;
    size_t off = 0;
    auto alloc = [&](size_t bytes) -> void* {
        void* p = ws + off;
        off += (bytes + 255) & ~(size_t)255;
        return p;
    };
    float* xw             = (float*)alloc((size_t)M_ * C_ * 4);
    unsigned short* comb  = (unsigned short*)alloc((size_t)M_ * 1024 * 2);
    unsigned short* qkvh  = (unsigned short*)alloc((size_t)M_ * 1536 * 2);
    unsigned short* qkvl  = (unsigned short*)alloc((size_t)M_ * 1536 * 2);
    unsigned short* ctx   = (unsigned short*)alloc((size_t)M_ * 512 * 2);
    float* smask          = (float*)alloc((size_t)M_ * 4);
    unsigned short* w1b   = (unsigned short*)alloc(131072 * 2);
    unsigned short* inwb  = (unsigned short*)alloc(786432 * 2);
    unsigned short* outwb = (unsigned short*)alloc(262144 * 2);
    (void)ws_size; (void)in_sizes; (void)n_in; (void)out_size;

    k_walze_cvt<<<B_ * C_, 256, 0, stream>>>(x, dw_w, dw_b, sh_w, sh_b, mix_w,
                                             bn_g, bn_b, xw,
                                             det_w1, inp_w, outp_w, w1b, inwb, outwb);
    k_pack<<<dim3(16, 8, 8), 256, 0, stream>>>(x, xw, comb);
    k_det_qkv<<<512 + 768, 256, 0, stream>>>(comb, w1b, det_b1, det_w2, det_b2, smask,
                                             inwb, inp_b, qkvh, qkvl);
    k_attn<<<dim3(16, NH_, B_), 256, 0, stream>>>(qkvh, qkvl, ctx);
    k_out_combine<<<dim3(M_ / 64, C_ / 64), 256, 0, stream>>>(outwb, ctx, outp_b,
                                                              xw, smask, out);
}